// Round 1
// baseline (1008.166 us; speedup 1.0000x reference)
//
#include <hip/hip_runtime.h>
#include <math.h>
#include <stdint.h>

#define RR 8192
#define DD 1024
#define KCLS 1203
#define KP 1204
#define MM 128
#define TOPKN 300
#define NFLAT (KCLS * MM)
#define NEGV (-1e9f)
#define SCLAMP 4.1351665567423563f

__device__ __forceinline__ unsigned fmono(float f) {
  unsigned u = __float_as_uint(f);
  return (u & 0x80000000u) ? ~u : (u | 0x80000000u);
}
__device__ __forceinline__ float monof(unsigned u) {
  return __uint_as_float((u & 0x80000000u) ? (u ^ 0x80000000u) : ~u);
}
__device__ __forceinline__ float iou_f(float4 a, float4 b) {
  float areaA = (a.z - a.x) * (a.w - a.y);
  float areaB = (b.z - b.x) * (b.w - b.y);
  float lx = fmaxf(a.x, b.x), ly = fmaxf(a.y, b.y);
  float rx = fminf(a.z, b.z), ry = fminf(a.w, b.w);
  float w = fmaxf(rx - lx, 0.f), h = fmaxf(ry - ly, 0.f);
  float inter = w * h;
  return inter / (areaA + areaB - inter + 1e-6f);
}

// ---------------- GEMM: logits = feat @ w_cls + b_cls, fp64-chunk accumulation -------------
// BM=BN=64, BK=16, 256 threads, 4x4 per-thread tile.
template <typename ZT>
__global__ __launch_bounds__(256) void k_gemm(const float* __restrict__ feat,
                                              const float* __restrict__ wcls,
                                              const float* __restrict__ bcls,
                                              ZT* __restrict__ out) {
  __shared__ float As[16][64];
  __shared__ float Bs[16][64];
  const int tid = threadIdx.x;
  const int c0 = blockIdx.x * 64;
  const int r0 = blockIdx.y * 64;
  const int tx4 = (tid & 15) << 2;
  const int ty4 = (tid >> 4) << 2;
  const int arow = tid >> 2, akq = (tid & 3) << 2;
  const int bk = tid >> 4, bcol = (tid & 15) << 2;

  float fa[4][4];
  double da[4][4];
#pragma unroll
  for (int i = 0; i < 4; i++)
#pragma unroll
    for (int j = 0; j < 4; j++) { fa[i][j] = 0.f; da[i][j] = 0.0; }

  for (int kt = 0; kt < DD / 16; ++kt) {
    float4 av = *(const float4*)&feat[(size_t)(r0 + arow) * DD + kt * 16 + akq];
    float4 bv;
    {
      int gc = c0 + bcol;
      const float* wrow = &wcls[(size_t)(kt * 16 + bk) * KP];
      if (gc + 3 < KP) {
        bv = *(const float4*)&wrow[gc];
      } else {
        bv.x = (gc + 0 < KP) ? wrow[gc + 0] : 0.f;
        bv.y = (gc + 1 < KP) ? wrow[gc + 1] : 0.f;
        bv.z = (gc + 2 < KP) ? wrow[gc + 2] : 0.f;
        bv.w = (gc + 3 < KP) ? wrow[gc + 3] : 0.f;
      }
    }
    __syncthreads();
    As[akq + 0][arow] = av.x;
    As[akq + 1][arow] = av.y;
    As[akq + 2][arow] = av.z;
    As[akq + 3][arow] = av.w;
    *(float4*)&Bs[bk][bcol] = bv;
    __syncthreads();
#pragma unroll
    for (int k = 0; k < 16; ++k) {
      float4 a = *(const float4*)&As[k][ty4];
      float4 b = *(const float4*)&Bs[k][tx4];
      float ax[4] = {a.x, a.y, a.z, a.w};
      float bx[4] = {b.x, b.y, b.z, b.w};
#pragma unroll
      for (int i = 0; i < 4; i++)
#pragma unroll
        for (int j = 0; j < 4; j++) fa[i][j] = fmaf(ax[i], bx[j], fa[i][j]);
    }
    // fold fp32 chunk into fp64 accumulator (precision: keeps logit error ~1e-7)
#pragma unroll
    for (int i = 0; i < 4; i++)
#pragma unroll
      for (int j = 0; j < 4; j++) { da[i][j] += (double)fa[i][j]; fa[i][j] = 0.f; }
  }
#pragma unroll
  for (int i = 0; i < 4; i++) {
    int r = r0 + ty4 + i;
#pragma unroll
    for (int j = 0; j < 4; j++) {
      int c = c0 + tx4 + j;
      if (c < KP) out[(size_t)r * KP + c] = (ZT)(da[i][j] + (double)bcls[c]);
    }
  }
}

// ---------------- per-row max and sum(exp(z-max)) in double -----------------
template <typename ZT>
__global__ __launch_bounds__(256) void k_rowstats(const ZT* __restrict__ z,
                                                  double* __restrict__ rmax,
                                                  double* __restrict__ rsum) {
  const int r = blockIdx.x;
  const int tid = threadIdx.x;
  __shared__ double red[256];
  double m = -1e300;
  for (int c = tid; c < KP; c += 256) m = fmax(m, (double)z[(size_t)r * KP + c]);
  red[tid] = m;
  __syncthreads();
  for (int off = 128; off; off >>= 1) {
    if (tid < off) red[tid] = fmax(red[tid], red[tid + off]);
    __syncthreads();
  }
  m = red[0];
  __syncthreads();
  double s = 0.0;
  for (int c = tid; c < KP; c += 256) s += exp((double)z[(size_t)r * KP + c] - m);
  red[tid] = s;
  __syncthreads();
  for (int off = 128; off; off >>= 1) {
    if (tid < off) red[tid] += red[tid + off];
    __syncthreads();
  }
  if (tid == 0) { rmax[r] = m; rsum[r] = red[0]; }
}

// ---------------- masked scores, transposed to [class][row] -----------------
template <typename ZT>
__global__ __launch_bounds__(256) void k_scores(const ZT* __restrict__ z,
                                                const double* __restrict__ rmax,
                                                const double* __restrict__ rsum,
                                                float* __restrict__ scoresT) {
  __shared__ float st[64][65];
  const int c0 = blockIdx.x * 64, r0 = blockIdx.y * 64;
  const int tid = threadIdx.x;
  const int cc = tid & 63, rq = tid >> 6;
  for (int it = 0; it < 16; ++it) {
    int r = r0 + it * 4 + rq;
    int c = c0 + cc;
    if (c < KCLS) {
      double zz = (double)z[(size_t)r * KP + c];
      double sc = exp(zz - rmax[r]) / rsum[r];
      float f = (float)sc;
      st[cc][it * 4 + rq] = (f > 1e-4f) ? f : NEGV;
    }
  }
  __syncthreads();
  const int rr = tid & 63, cq = tid >> 6;
  for (int it = 0; it < 16; ++it) {
    int c = c0 + it * 4 + cq;
    if (c < KCLS) scoresT[(size_t)c * RR + r0 + rr] = st[it * 4 + cq][rr];
  }
}

// ---------------- box deltas (GEMV) + apply + clip -----------------
__global__ __launch_bounds__(256) void k_boxes(const float* __restrict__ feat,
                                               const float* __restrict__ wbox,
                                               const float* __restrict__ bbox,
                                               const float* __restrict__ props,
                                               float* __restrict__ boxes) {
  const int wid = threadIdx.x >> 6, lane = threadIdx.x & 63;
  const int r = blockIdx.x * 4 + wid;
  float p0 = 0, p1 = 0, p2 = 0, p3 = 0;
  for (int k = lane; k < DD; k += 64) {
    float f = feat[(size_t)r * DD + k];
    float4 w = *(const float4*)&wbox[k * 4];
    p0 = fmaf(f, w.x, p0);
    p1 = fmaf(f, w.y, p1);
    p2 = fmaf(f, w.z, p2);
    p3 = fmaf(f, w.w, p3);
  }
  for (int off = 32; off; off >>= 1) {
    p0 += __shfl_down(p0, off);
    p1 += __shfl_down(p1, off);
    p2 += __shfl_down(p2, off);
    p3 += __shfl_down(p3, off);
  }
  if (lane == 0) {
    p0 += bbox[0]; p1 += bbox[1]; p2 += bbox[2]; p3 += bbox[3];
    float4 pr = *(const float4*)&props[r * 4];
    float w = pr.z - pr.x, h = pr.w - pr.y;
    float cx = pr.x + 0.5f * w, cy = pr.y + 0.5f * h;
    float dx = p0 / 10.f, dy = p1 / 10.f;
    float dw = fminf(p2 / 5.f, SCLAMP), dh = fminf(p3 / 5.f, SCLAMP);
    float pcx = dx * w + cx, pcy = dy * h + cy;
    float pw = expf(dw) * w, ph = expf(dh) * h;
    float x1 = pcx - 0.5f * pw, y1 = pcy - 0.5f * ph;
    float x2 = pcx + 0.5f * pw, y2 = pcy + 0.5f * ph;
    x1 = fminf(fmaxf(x1, 0.f), 1333.f);
    x2 = fminf(fmaxf(x2, 0.f), 1333.f);
    y1 = fminf(fmaxf(y1, 0.f), 800.f);
    y2 = fminf(fmaxf(y2, 0.f), 800.f);
    *(float4*)&boxes[r * 4] = make_float4(x1, y1, x2, y2);
  }
}

// ---------------- per-class exact top-128 (radix-select on unique key) + NMS -----------------
// key = (monotone_float << 13) | (8191 - idx): descending value, ascending index — lax.top_k tie order.
template <bool DIRECT>
__global__ __launch_bounds__(256) void k_class(const float* __restrict__ scoresT,
                                               const float* __restrict__ lgf,
                                               const double* __restrict__ rmax,
                                               const double* __restrict__ rsum,
                                               const float* __restrict__ boxes,
                                               float* __restrict__ per_scores,
                                               int* __restrict__ per_idx) {
  const int c = blockIdx.x, tid = threadIdx.x;
  __shared__ float sval[RR];
  __shared__ unsigned hist[256];
  __shared__ unsigned cum[256];
  __shared__ uint64_t skey[MM];
  __shared__ float4 sbox[MM];
  __shared__ int skeep[MM];
  __shared__ uint64_t s_prefix;
  __shared__ int s_need, s_cnt, s_supp;

  for (int r2 = tid; r2 < RR; r2 += 256) {
    float s;
    if (DIRECT) {
      double sc = exp((double)lgf[(size_t)r2 * KP + c] - rmax[r2]) / rsum[r2];
      float f = (float)sc;
      s = (f > 1e-4f) ? f : NEGV;
    } else {
      s = scoresT[(size_t)c * RR + r2];
    }
    sval[r2] = s;
  }
  if (tid == 0) { s_prefix = 0; s_need = MM; s_cnt = 0; }
  if (tid < MM) skey[tid] = 0;
  __syncthreads();

  for (int pass = 0; pass < 6; ++pass) {
    const int shift = 40 - 8 * pass;
    hist[tid] = 0;
    __syncthreads();
    uint64_t pre = s_prefix;
    int nd = s_need;
    for (int r2 = tid; r2 < RR; r2 += 256) {
      uint64_t key = ((uint64_t)fmono(sval[r2]) << 13) | (uint64_t)(8191 - r2);
      if ((key >> (shift + 8)) == (pre >> (shift + 8)))
        atomicAdd(&hist[(unsigned)(key >> shift) & 255u], 1u);
    }
    __syncthreads();
    cum[tid] = hist[tid];
    __syncthreads();
    for (int off = 1; off < 256; off <<= 1) {
      unsigned add = (tid + off < 256) ? cum[tid + off] : 0u;
      __syncthreads();
      cum[tid] += add;
      __syncthreads();
    }
    unsigned mycum = cum[tid];
    unsigned nxt = (tid < 255) ? cum[tid + 1] : 0u;
    if ((int)mycum >= nd && (int)nxt < nd) {
      s_prefix = pre | ((uint64_t)tid << shift);
      s_need = nd - (int)nxt;
    }
    __syncthreads();
  }
  const uint64_t kthr = s_prefix;
  for (int r2 = tid; r2 < RR; r2 += 256) {
    uint64_t key = ((uint64_t)fmono(sval[r2]) << 13) | (uint64_t)(8191 - r2);
    if (key >= kthr) {
      int p = atomicAdd(&s_cnt, 1);
      if (p < MM) skey[p] = key;
    }
  }
  __syncthreads();
  // bitonic sort 128 keys descending
  for (int kk2 = 2; kk2 <= MM; kk2 <<= 1)
    for (int j = kk2 >> 1; j > 0; j >>= 1) {
      __syncthreads();
      if (tid < MM) {
        int ixj = tid ^ j;
        if (ixj > tid) {
          uint64_t a = skey[tid], b = skey[ixj];
          bool desc = ((tid & kk2) == 0);
          if (desc ? (a < b) : (a > b)) { skey[tid] = b; skey[ixj] = a; }
        }
      }
    }
  __syncthreads();
  float myval = 0.f;
  int myidx = 0;
  bool valid = false;
  float4 mybox = make_float4(0, 0, 0, 0);
  if (tid < MM) {
    uint64_t key = skey[tid];
    myidx = 8191 - (int)(key & 0x1FFFu);
    myval = monof((unsigned)(key >> 13));
    valid = myval > -5e8f;
    mybox = *(const float4*)&boxes[myidx * 4];
    sbox[tid] = mybox;
    skeep[tid] = 0;
  }
  __syncthreads();
  for (int i = 0; i < MM; ++i) {
    if (tid == 0) s_supp = 0;
    __syncthreads();
    if (tid < i && skeep[tid]) {
      if (iou_f(mybox, sbox[i]) > 0.5f) s_supp = 1;
    }
    __syncthreads();
    if (tid == i) skeep[i] = (valid && !s_supp) ? 1 : 0;
  }
  __syncthreads();
  if (tid < MM) {
    per_scores[(size_t)c * MM + tid] = skeep[tid] ? myval : NEGV;
    per_idx[(size_t)c * MM + tid] = myidx;
  }
}

// ---------------- global top-300 + gather output -----------------
__global__ __launch_bounds__(1024) void k_top300(const float* __restrict__ per_scores,
                                                 const int* __restrict__ per_idx,
                                                 const float* __restrict__ boxes,
                                                 float* __restrict__ out) {
  const int tid = threadIdx.x;
  __shared__ unsigned hist[256], cum[256];
  __shared__ uint64_t skey[512];
  __shared__ uint64_t s_prefix;
  __shared__ int s_need, s_cnt;
  if (tid == 0) { s_prefix = 0; s_need = TOPKN; s_cnt = 0; }
  if (tid < 512) skey[tid] = 0;
  __syncthreads();
  for (int pass = 0; pass < 7; ++pass) {
    const int shift = 48 - 8 * pass;
    if (tid < 256) hist[tid] = 0;
    __syncthreads();
    uint64_t pre = s_prefix;
    int nd = s_need;
    for (int f = tid; f < NFLAT; f += 1024) {
      uint64_t key = ((uint64_t)fmono(per_scores[f]) << 18) | (uint64_t)(262143 - f);
      if ((key >> (shift + 8)) == (pre >> (shift + 8)))
        atomicAdd(&hist[(unsigned)(key >> shift) & 255u], 1u);
    }
    __syncthreads();
    if (tid < 256) cum[tid] = hist[tid];
    __syncthreads();
    for (int off = 1; off < 256; off <<= 1) {
      unsigned add = 0;
      if (tid < 256 && tid + off < 256) add = cum[tid + off];
      __syncthreads();
      if (tid < 256) cum[tid] += add;
      __syncthreads();
    }
    if (tid < 256) {
      unsigned mycum = cum[tid], nxt = (tid < 255) ? cum[tid + 1] : 0u;
      if ((int)mycum >= nd && (int)nxt < nd) {
        s_prefix = pre | ((uint64_t)tid << shift);
        s_need = nd - (int)nxt;
      }
    }
    __syncthreads();
  }
  const uint64_t kthr = s_prefix;
  for (int f = tid; f < NFLAT; f += 1024) {
    uint64_t key = ((uint64_t)fmono(per_scores[f]) << 18) | (uint64_t)(262143 - f);
    if (key >= kthr) {
      int p = atomicAdd(&s_cnt, 1);
      if (p < 512) skey[p] = key;
    }
  }
  __syncthreads();
  for (int kk2 = 2; kk2 <= 512; kk2 <<= 1)
    for (int j = kk2 >> 1; j > 0; j >>= 1) {
      __syncthreads();
      if (tid < 512) {
        int ixj = tid ^ j;
        if (ixj > tid) {
          uint64_t a = skey[tid], b = skey[ixj];
          bool desc = ((tid & kk2) == 0);
          if (desc ? (a < b) : (a > b)) { skey[tid] = b; skey[ixj] = a; }
        }
      }
    }
  __syncthreads();
  if (tid < TOPKN) {
    uint64_t key = skey[tid];
    int f = 262143 - (int)(key & 0x3FFFFu);
    float val = monof((unsigned)(key >> 18));
    int cls = f >> 7;  // f / M
    int prop = per_idx[f];
    float4 b = *(const float4*)&boxes[prop * 4];
    float* o = &out[tid * 6];
    o[0] = b.x; o[1] = b.y; o[2] = b.z; o[3] = b.w;
    o[4] = val; o[5] = (float)cls;
  }
}

extern "C" void kernel_launch(void* const* d_in, const int* in_sizes, int n_in,
                              void* d_out, int out_size, void* d_ws, size_t ws_size,
                              hipStream_t stream) {
  const float* feat = (const float*)d_in[0];
  const float* props = (const float*)d_in[1];
  const float* wcls = (const float*)d_in[2];
  const float* bcls = (const float*)d_in[3];
  const float* wbox = (const float*)d_in[4];
  const float* bbox = (const float*)d_in[5];
  float* out = (float*)d_out;
  char* ws = (char*)d_ws;

  size_t o = 0;
  auto al = [&](size_t b) { size_t cur = o; o += (b + 255) & ~(size_t)255; return cur; };
  const size_t o_boxes = al((size_t)RR * 4 * 4);
  const size_t o_ps = al((size_t)KCLS * MM * 4);
  const size_t o_pi = al((size_t)KCLS * MM * 4);
  const size_t o_rmax = al((size_t)RR * 8);
  const size_t o_rsum = al((size_t)RR * 8);
  const size_t fixed_end = o;
  const size_t sz_scT = ((size_t)KCLS * RR * 4 + 255) & ~(size_t)255;
  const size_t sz_lgD = ((size_t)RR * KP * 8 + 255) & ~(size_t)255;
  const size_t sz_lgF = ((size_t)RR * KP * 4 + 255) & ~(size_t)255;

  float* boxes = (float*)(ws + o_boxes);
  float* per_scores = (float*)(ws + o_ps);
  int* per_idx = (int*)(ws + o_pi);
  double* rmax = (double*)(ws + o_rmax);
  double* rsum = (double*)(ws + o_rsum);

  const bool pathA = ws_size >= fixed_end + sz_scT + sz_lgD;  // double logits + scoresT
  const bool pathB = !pathA && ws_size >= fixed_end + sz_scT + sz_lgF;  // float logits + scoresT

  dim3 gGemm(19, 128);

  k_boxes<<<RR / 4, 256, 0, stream>>>(feat, wbox, bbox, props, boxes);

  if (pathA) {
    float* scoresT = (float*)(ws + fixed_end);
    double* lg = (double*)(ws + fixed_end + sz_scT);
    k_gemm<double><<<gGemm, 256, 0, stream>>>(feat, wcls, bcls, lg);
    k_rowstats<double><<<RR, 256, 0, stream>>>(lg, rmax, rsum);
    k_scores<double><<<gGemm, 256, 0, stream>>>(lg, rmax, rsum, scoresT);
    k_class<false><<<KCLS, 256, 0, stream>>>(scoresT, nullptr, rmax, rsum, boxes, per_scores, per_idx);
  } else if (pathB) {
    float* scoresT = (float*)(ws + fixed_end);
    float* lg = (float*)(ws + fixed_end + sz_scT);
    k_gemm<float><<<gGemm, 256, 0, stream>>>(feat, wcls, bcls, lg);
    k_rowstats<float><<<RR, 256, 0, stream>>>(lg, rmax, rsum);
    k_scores<float><<<gGemm, 256, 0, stream>>>(lg, rmax, rsum, scoresT);
    k_class<false><<<KCLS, 256, 0, stream>>>(scoresT, nullptr, rmax, rsum, boxes, per_scores, per_idx);
  } else {
    // minimal-memory fallback: float logits only, per-class direct column reads
    float* lg = (float*)(ws + fixed_end);
    k_gemm<float><<<gGemm, 256, 0, stream>>>(feat, wcls, bcls, lg);
    k_rowstats<float><<<RR, 256, 0, stream>>>(lg, rmax, rsum);
    k_class<true><<<KCLS, 256, 0, stream>>>(nullptr, lg, rmax, rsum, boxes, per_scores, per_idx);
  }

  k_top300<<<1, 1024, 0, stream>>>(per_scores, per_idx, boxes, out);
}

// Round 3
// 826.329 us; speedup vs baseline: 1.2201x; 1.2201x over previous
//
#include <hip/hip_runtime.h>
#include <math.h>
#include <stdint.h>

#define RR 8192
#define DD 1024
#define KCLS 1203
#define KP 1204
#define MM 128
#define TOPKN 300
#define NFLAT (KCLS * MM)
#define NEGV (-1e9f)
#define SCLAMP 4.1351665567423563f

__device__ __forceinline__ unsigned fmono(float f) {
  unsigned u = __float_as_uint(f);
  return (u & 0x80000000u) ? ~u : (u | 0x80000000u);
}
__device__ __forceinline__ float monof(unsigned u) {
  return __uint_as_float((u & 0x80000000u) ? (u ^ 0x80000000u) : ~u);
}
__device__ __forceinline__ float iou_f(float4 a, float4 b) {
  float areaA = (a.z - a.x) * (a.w - a.y);
  float areaB = (b.z - b.x) * (b.w - b.y);
  float lx = fmaxf(a.x, b.x), ly = fmaxf(a.y, b.y);
  float rx = fminf(a.z, b.z), ry = fminf(a.w, b.w);
  float w = fmaxf(rx - lx, 0.f), h = fmaxf(ry - ly, 0.f);
  float inter = w * h;
  return inter / (areaA + areaB - inter + 1e-6f);
}

// ---------------- GEMM: logits = feat @ w_cls + b_cls, fp64-chunk accumulation -------------
template <typename ZT>
__global__ __launch_bounds__(256) void k_gemm(const float* __restrict__ feat,
                                              const float* __restrict__ wcls,
                                              const float* __restrict__ bcls,
                                              ZT* __restrict__ out) {
  __shared__ float As[16][64];
  __shared__ float Bs[16][64];
  const int tid = threadIdx.x;
  const int c0 = blockIdx.x * 64;
  const int r0 = blockIdx.y * 64;
  const int tx4 = (tid & 15) << 2;
  const int ty4 = (tid >> 4) << 2;
  const int arow = tid >> 2, akq = (tid & 3) << 2;
  const int bk = tid >> 4, bcol = (tid & 15) << 2;

  float fa[4][4];
  double da[4][4];
#pragma unroll
  for (int i = 0; i < 4; i++)
#pragma unroll
    for (int j = 0; j < 4; j++) { fa[i][j] = 0.f; da[i][j] = 0.0; }

  for (int kt = 0; kt < DD / 16; ++kt) {
    float4 av = *(const float4*)&feat[(size_t)(r0 + arow) * DD + kt * 16 + akq];
    float4 bv;
    {
      int gc = c0 + bcol;
      const float* wrow = &wcls[(size_t)(kt * 16 + bk) * KP];
      if (gc + 3 < KP) {
        bv = *(const float4*)&wrow[gc];
      } else {
        bv.x = (gc + 0 < KP) ? wrow[gc + 0] : 0.f;
        bv.y = (gc + 1 < KP) ? wrow[gc + 1] : 0.f;
        bv.z = (gc + 2 < KP) ? wrow[gc + 2] : 0.f;
        bv.w = (gc + 3 < KP) ? wrow[gc + 3] : 0.f;
      }
    }
    __syncthreads();
    As[akq + 0][arow] = av.x;
    As[akq + 1][arow] = av.y;
    As[akq + 2][arow] = av.z;
    As[akq + 3][arow] = av.w;
    *(float4*)&Bs[bk][bcol] = bv;
    __syncthreads();
#pragma unroll
    for (int k = 0; k < 16; ++k) {
      float4 a = *(const float4*)&As[k][ty4];
      float4 b = *(const float4*)&Bs[k][tx4];
      float ax[4] = {a.x, a.y, a.z, a.w};
      float bx[4] = {b.x, b.y, b.z, b.w};
#pragma unroll
      for (int i = 0; i < 4; i++)
#pragma unroll
        for (int j = 0; j < 4; j++) fa[i][j] = fmaf(ax[i], bx[j], fa[i][j]);
    }
#pragma unroll
    for (int i = 0; i < 4; i++)
#pragma unroll
      for (int j = 0; j < 4; j++) { da[i][j] += (double)fa[i][j]; fa[i][j] = 0.f; }
  }
#pragma unroll
  for (int i = 0; i < 4; i++) {
    int r = r0 + ty4 + i;
#pragma unroll
    for (int j = 0; j < 4; j++) {
      int c = c0 + tx4 + j;
      if (c < KP) out[(size_t)r * KP + c] = (ZT)(da[i][j] + (double)bcls[c]);
    }
  }
}

// ---------------- per-row max and sum(exp(z-max)) in double -----------------
template <typename ZT>
__global__ __launch_bounds__(256) void k_rowstats(const ZT* __restrict__ z,
                                                  double* __restrict__ rmax,
                                                  double* __restrict__ rsum) {
  const int r = blockIdx.x;
  const int tid = threadIdx.x;
  __shared__ double red[256];
  double m = -1e300;
  for (int c = tid; c < KP; c += 256) m = fmax(m, (double)z[(size_t)r * KP + c]);
  red[tid] = m;
  __syncthreads();
  for (int off = 128; off; off >>= 1) {
    if (tid < off) red[tid] = fmax(red[tid], red[tid + off]);
    __syncthreads();
  }
  m = red[0];
  __syncthreads();
  double s = 0.0;
  for (int c = tid; c < KP; c += 256) s += exp((double)z[(size_t)r * KP + c] - m);
  red[tid] = s;
  __syncthreads();
  for (int off = 128; off; off >>= 1) {
    if (tid < off) red[tid] += red[tid + off];
    __syncthreads();
  }
  if (tid == 0) { rmax[r] = m; rsum[r] = red[0]; }
}

// ---------------- masked scores, transposed to [class][row] -----------------
template <typename ZT>
__global__ __launch_bounds__(256) void k_scores(const ZT* __restrict__ z,
                                                const double* __restrict__ rmax,
                                                const double* __restrict__ rsum,
                                                float* __restrict__ scoresT) {
  __shared__ float st[64][65];
  const int c0 = blockIdx.x * 64, r0 = blockIdx.y * 64;
  const int tid = threadIdx.x;
  const int cc = tid & 63, rq = tid >> 6;
  for (int it = 0; it < 16; ++it) {
    int r = r0 + it * 4 + rq;
    int c = c0 + cc;
    if (c < KCLS) {
      double zz = (double)z[(size_t)r * KP + c];
      double sc = exp(zz - rmax[r]) / rsum[r];
      float f = (float)sc;
      st[cc][it * 4 + rq] = (f > 1e-4f) ? f : NEGV;
    }
  }
  __syncthreads();
  const int rr = tid & 63, cq = tid >> 6;
  for (int it = 0; it < 16; ++it) {
    int c = c0 + it * 4 + cq;
    if (c < KCLS) scoresT[(size_t)c * RR + r0 + rr] = st[it * 4 + cq][rr];
  }
}

// ---------------- box deltas (GEMV) + apply + clip -----------------
__global__ __launch_bounds__(256) void k_boxes(const float* __restrict__ feat,
                                               const float* __restrict__ wbox,
                                               const float* __restrict__ bbox,
                                               const float* __restrict__ props,
                                               float* __restrict__ boxes) {
  const int wid = threadIdx.x >> 6, lane = threadIdx.x & 63;
  const int r = blockIdx.x * 4 + wid;
  float p0 = 0, p1 = 0, p2 = 0, p3 = 0;
  for (int k = lane; k < DD; k += 64) {
    float f = feat[(size_t)r * DD + k];
    float4 w = *(const float4*)&wbox[k * 4];
    p0 = fmaf(f, w.x, p0);
    p1 = fmaf(f, w.y, p1);
    p2 = fmaf(f, w.z, p2);
    p3 = fmaf(f, w.w, p3);
  }
  for (int off = 32; off; off >>= 1) {
    p0 += __shfl_down(p0, off);
    p1 += __shfl_down(p1, off);
    p2 += __shfl_down(p2, off);
    p3 += __shfl_down(p3, off);
  }
  if (lane == 0) {
    p0 += bbox[0]; p1 += bbox[1]; p2 += bbox[2]; p3 += bbox[3];
    float4 pr = *(const float4*)&props[r * 4];
    float w = pr.z - pr.x, h = pr.w - pr.y;
    float cx = pr.x + 0.5f * w, cy = pr.y + 0.5f * h;
    float dx = p0 / 10.f, dy = p1 / 10.f;
    float dw = fminf(p2 / 5.f, SCLAMP), dh = fminf(p3 / 5.f, SCLAMP);
    float pcx = dx * w + cx, pcy = dy * h + cy;
    float pw = expf(dw) * w, ph = expf(dh) * h;
    float x1 = pcx - 0.5f * pw, y1 = pcy - 0.5f * ph;
    float x2 = pcx + 0.5f * pw, y2 = pcy + 0.5f * ph;
    x1 = fminf(fmaxf(x1, 0.f), 1333.f);
    x2 = fminf(fmaxf(x2, 0.f), 1333.f);
    y1 = fminf(fmaxf(y1, 0.f), 800.f);
    y2 = fminf(fmaxf(y2, 0.f), 800.f);
    *(float4*)&boxes[r * 4] = make_float4(x1, y1, x2, y2);
  }
}

// ---------------- per-class exact top-128 + NMS; also feed global L1 histogram -----------------
template <bool DIRECT>
__global__ __launch_bounds__(256) void k_class(const float* __restrict__ scoresT,
                                               const float* __restrict__ lgf,
                                               const double* __restrict__ rmax,
                                               const double* __restrict__ rsum,
                                               const float* __restrict__ boxes,
                                               float* __restrict__ per_scores,
                                               int* __restrict__ per_idx,
                                               unsigned* __restrict__ hist1) {
  const int c = blockIdx.x, tid = threadIdx.x;
  __shared__ float sval[RR];
  __shared__ unsigned hist[256];
  __shared__ unsigned cum[256];
  __shared__ uint64_t skey[MM];
  __shared__ float4 sbox[MM];
  __shared__ int skeep[MM];
  __shared__ uint64_t s_prefix;
  __shared__ int s_need, s_cnt, s_supp;

  for (int r2 = tid; r2 < RR; r2 += 256) {
    float s;
    if (DIRECT) {
      double sc = exp((double)lgf[(size_t)r2 * KP + c] - rmax[r2]) / rsum[r2];
      float f = (float)sc;
      s = (f > 1e-4f) ? f : NEGV;
    } else {
      s = scoresT[(size_t)c * RR + r2];
    }
    sval[r2] = s;
  }
  if (tid == 0) { s_prefix = 0; s_need = MM; s_cnt = 0; }
  if (tid < MM) skey[tid] = 0;
  __syncthreads();

  for (int pass = 0; pass < 6; ++pass) {
    const int shift = 40 - 8 * pass;
    hist[tid] = 0;
    __syncthreads();
    uint64_t pre = s_prefix;
    int nd = s_need;
    for (int r2 = tid; r2 < RR; r2 += 256) {
      uint64_t key = ((uint64_t)fmono(sval[r2]) << 13) | (uint64_t)(8191 - r2);
      if ((key >> (shift + 8)) == (pre >> (shift + 8)))
        atomicAdd(&hist[(unsigned)(key >> shift) & 255u], 1u);
    }
    __syncthreads();
    cum[tid] = hist[tid];
    __syncthreads();
    for (int off = 1; off < 256; off <<= 1) {
      unsigned add = (tid + off < 256) ? cum[tid + off] : 0u;
      __syncthreads();
      cum[tid] += add;
      __syncthreads();
    }
    unsigned mycum = cum[tid];
    unsigned nxt = (tid < 255) ? cum[tid + 1] : 0u;
    if ((int)mycum >= nd && (int)nxt < nd) {
      s_prefix = pre | ((uint64_t)tid << shift);
      s_need = nd - (int)nxt;
    }
    __syncthreads();
  }
  const uint64_t kthr = s_prefix;
  for (int r2 = tid; r2 < RR; r2 += 256) {
    uint64_t key = ((uint64_t)fmono(sval[r2]) << 13) | (uint64_t)(8191 - r2);
    if (key >= kthr) {
      int p = atomicAdd(&s_cnt, 1);
      if (p < MM) skey[p] = key;
    }
  }
  __syncthreads();
  for (int kk2 = 2; kk2 <= MM; kk2 <<= 1)
    for (int j = kk2 >> 1; j > 0; j >>= 1) {
      __syncthreads();
      if (tid < MM) {
        int ixj = tid ^ j;
        if (ixj > tid) {
          uint64_t a = skey[tid], b = skey[ixj];
          bool desc = ((tid & kk2) == 0);
          if (desc ? (a < b) : (a > b)) { skey[tid] = b; skey[ixj] = a; }
        }
      }
    }
  __syncthreads();
  float myval = 0.f;
  int myidx = 0;
  bool valid = false;
  float4 mybox = make_float4(0, 0, 0, 0);
  if (tid < MM) {
    uint64_t key = skey[tid];
    myidx = 8191 - (int)(key & 0x1FFFu);
    myval = monof((unsigned)(key >> 13));
    valid = myval > -5e8f;
    mybox = *(const float4*)&boxes[myidx * 4];
    sbox[tid] = mybox;
    skeep[tid] = 0;
  }
  __syncthreads();
  for (int i = 0; i < MM; ++i) {
    if (tid == 0) s_supp = 0;
    __syncthreads();
    if (tid < i && skeep[tid]) {
      if (iou_f(mybox, sbox[i]) > 0.5f) s_supp = 1;
    }
    __syncthreads();
    if (tid == i) skeep[i] = (valid && !s_supp) ? 1 : 0;
  }
  __syncthreads();
  if (tid < MM) {
    per_scores[(size_t)c * MM + tid] = skeep[tid] ? myval : NEGV;
    per_idx[(size_t)c * MM + tid] = myidx;
    if (skeep[tid]) atomicAdd(&hist1[fmono(myval) >> 16], 1u);
  }
}

// ---------------- global top-300: two-level radix threshold + compact + small sort ----------
// sel[0]=p16  sel[1]=need within p16 bin  sel[2]=v32  sel[4]=def count  sel[5]=tie count
__global__ __launch_bounds__(1024) void k_sel1(const unsigned* __restrict__ hist, int* __restrict__ sel) {
  __shared__ unsigned red[1024];
  const int t = threadIdx.x;
  unsigned s = 0;
#pragma unroll 8
  for (int i = 0; i < 64; i++) s += hist[t * 64 + i];
  red[t] = s;
  __syncthreads();
  for (int off = 1; off < 1024; off <<= 1) {
    unsigned add = (t + off < 1024) ? red[t + off] : 0u;
    __syncthreads();
    red[t] += add;
    __syncthreads();
  }
  unsigned above = (t < 1023) ? red[t + 1] : 0u;
  if (red[t] >= (unsigned)TOPKN && above < (unsigned)TOPKN) {
    unsigned run = above;
    for (int b = 63; b >= 0; --b) {
      unsigned cb = hist[t * 64 + b];
      if (run < (unsigned)TOPKN && run + cb >= (unsigned)TOPKN) {
        sel[0] = t * 64 + b;
        sel[1] = (int)((unsigned)TOPKN - run);
      }
      run += cb;
    }
  }
}

__global__ __launch_bounds__(256) void k_hist2(const float* __restrict__ per_scores,
                                               const int* __restrict__ sel,
                                               unsigned* __restrict__ hist2) {
  const int f = blockIdx.x * 256 + threadIdx.x;
  if (f >= NFLAT) return;
  const unsigned p16 = (unsigned)sel[0];
  unsigned u = fmono(per_scores[f]);
  if ((u >> 16) == p16) atomicAdd(&hist2[u & 0xFFFFu], 1u);
}

__global__ __launch_bounds__(1024) void k_sel2(const unsigned* __restrict__ hist, int* __restrict__ sel) {
  __shared__ unsigned red[1024];
  __shared__ unsigned sneed, sp16;
  const int t = threadIdx.x;
  if (t == 0) { sneed = (unsigned)sel[1]; sp16 = (unsigned)sel[0]; }
  __syncthreads();
  const unsigned NEED = sneed;
  unsigned s = 0;
#pragma unroll 8
  for (int i = 0; i < 64; i++) s += hist[t * 64 + i];
  red[t] = s;
  __syncthreads();
  for (int off = 1; off < 1024; off <<= 1) {
    unsigned add = (t + off < 1024) ? red[t + off] : 0u;
    __syncthreads();
    red[t] += add;
    __syncthreads();
  }
  unsigned above = (t < 1023) ? red[t + 1] : 0u;
  if (red[t] >= NEED && above < NEED) {
    unsigned run = above;
    for (int b = 63; b >= 0; --b) {
      unsigned cb = hist[t * 64 + b];
      if (run < NEED && run + cb >= NEED) {
        sel[2] = (int)((sp16 << 16) | (unsigned)(t * 64 + b));
      }
      run += cb;
    }
  }
}

__global__ __launch_bounds__(256) void k_compact(const float* __restrict__ per_scores,
                                                 int* __restrict__ sel,
                                                 uint64_t* __restrict__ deflist,
                                                 uint64_t* __restrict__ tielist) {
  const int f = blockIdx.x * 256 + threadIdx.x;
  if (f >= NFLAT) return;
  const unsigned v32 = (unsigned)sel[2];
  unsigned u = fmono(per_scores[f]);
  if (u < v32) return;
  uint64_t key = ((uint64_t)u << 18) | (uint64_t)(262143 - f);
  if (u > v32) {
    int p = atomicAdd(&sel[4], 1);
    if (p < 512) deflist[p] = key;
  } else {
    int p = atomicAdd(&sel[5], 1);
    if (p < 512) tielist[p] = key;
  }
}

__global__ __launch_bounds__(1024) void k_final(const uint64_t* __restrict__ deflist,
                                                const uint64_t* __restrict__ tielist,
                                                const int* __restrict__ sel,
                                                const int* __restrict__ per_idx,
                                                const float* __restrict__ boxes,
                                                float* __restrict__ out) {
  __shared__ uint64_t skey[1024];
  const int t = threadIdx.x;
  const int n0 = min(sel[4], 512);
  const int n1 = min(sel[5], 512);
  uint64_t k = 0;
  if (t < n0) k = deflist[t];
  else if (t - n0 < n1) k = tielist[t - n0];
  skey[t] = k;
  __syncthreads();
  for (int kk2 = 2; kk2 <= 1024; kk2 <<= 1)
    for (int j = kk2 >> 1; j > 0; j >>= 1) {
      __syncthreads();
      int ixj = t ^ j;
      if (ixj > t) {
        uint64_t a = skey[t], b = skey[ixj];
        bool desc = ((t & kk2) == 0);
        if (desc ? (a < b) : (a > b)) { skey[t] = b; skey[ixj] = a; }
      }
    }
  __syncthreads();
  if (t < TOPKN) {
    uint64_t key = skey[t];
    int f = 262143 - (int)(key & 0x3FFFFu);
    float val = monof((unsigned)(key >> 18));
    int cls = f >> 7;
    int prop = per_idx[f];
    float4 b = *(const float4*)&boxes[prop * 4];
    float* o = &out[t * 6];
    o[0] = b.x; o[1] = b.y; o[2] = b.z; o[3] = b.w;
    o[4] = val; o[5] = (float)cls;
  }
}

extern "C" void kernel_launch(void* const* d_in, const int* in_sizes, int n_in,
                              void* d_out, int out_size, void* d_ws, size_t ws_size,
                              hipStream_t stream) {
  const float* feat = (const float*)d_in[0];
  const float* props = (const float*)d_in[1];
  const float* wcls = (const float*)d_in[2];
  const float* bcls = (const float*)d_in[3];
  const float* wbox = (const float*)d_in[4];
  const float* bbox = (const float*)d_in[5];
  float* out = (float*)d_out;
  char* ws = (char*)d_ws;

  size_t o = 0;
  auto al = [&](size_t b) { size_t cur = o; o += (b + 255) & ~(size_t)255; return cur; };
  const size_t o_boxes = al((size_t)RR * 4 * 4);
  const size_t o_ps = al((size_t)KCLS * MM * 4);
  const size_t o_pi = al((size_t)KCLS * MM * 4);
  const size_t o_rmax = al((size_t)RR * 8);
  const size_t o_rsum = al((size_t)RR * 8);
  const size_t o_hist1 = al((size_t)65536 * 4);
  const size_t o_hist2 = al((size_t)65536 * 4);
  const size_t o_sel = al((size_t)256);
  const size_t o_def = al((size_t)512 * 8);
  const size_t o_tie = al((size_t)512 * 8);
  const size_t fixed_end = o;
  const size_t sz_scT = ((size_t)KCLS * RR * 4 + 255) & ~(size_t)255;
  const size_t sz_lgD = ((size_t)RR * KP * 8 + 255) & ~(size_t)255;
  const size_t sz_lgF = ((size_t)RR * KP * 4 + 255) & ~(size_t)255;

  float* boxes = (float*)(ws + o_boxes);
  float* per_scores = (float*)(ws + o_ps);
  int* per_idx = (int*)(ws + o_pi);
  double* rmax = (double*)(ws + o_rmax);
  double* rsum = (double*)(ws + o_rsum);
  unsigned* hist1 = (unsigned*)(ws + o_hist1);
  unsigned* hist2 = (unsigned*)(ws + o_hist2);
  int* sel = (int*)(ws + o_sel);
  uint64_t* deflist = (uint64_t*)(ws + o_def);
  uint64_t* tielist = (uint64_t*)(ws + o_tie);

  const bool pathA = ws_size >= fixed_end + sz_scT + sz_lgD;
  const bool pathB = !pathA && ws_size >= fixed_end + sz_scT + sz_lgF;

  dim3 gGemm(19, 128);
  const int gFlat = (NFLAT + 255) / 256;

  // zero hist1+hist2+sel (contiguous region)
  hipMemsetAsync(ws + o_hist1, 0, (o_sel - o_hist1) + 256, stream);

  k_boxes<<<RR / 4, 256, 0, stream>>>(feat, wbox, bbox, props, boxes);

  if (pathA) {
    float* scoresT = (float*)(ws + fixed_end);
    double* lg = (double*)(ws + fixed_end + sz_scT);
    k_gemm<double><<<gGemm, 256, 0, stream>>>(feat, wcls, bcls, lg);
    k_rowstats<double><<<RR, 256, 0, stream>>>(lg, rmax, rsum);
    k_scores<double><<<gGemm, 256, 0, stream>>>(lg, rmax, rsum, scoresT);
    k_class<false><<<KCLS, 256, 0, stream>>>(scoresT, nullptr, rmax, rsum, boxes, per_scores, per_idx, hist1);
  } else if (pathB) {
    float* scoresT = (float*)(ws + fixed_end);
    float* lg = (float*)(ws + fixed_end + sz_scT);
    k_gemm<float><<<gGemm, 256, 0, stream>>>(feat, wcls, bcls, lg);
    k_rowstats<float><<<RR, 256, 0, stream>>>(lg, rmax, rsum);
    k_scores<float><<<gGemm, 256, 0, stream>>>(lg, rmax, rsum, scoresT);
    k_class<false><<<KCLS, 256, 0, stream>>>(scoresT, nullptr, rmax, rsum, boxes, per_scores, per_idx, hist1);
  } else {
    float* lg = (float*)(ws + fixed_end);
    k_gemm<float><<<gGemm, 256, 0, stream>>>(feat, wcls, bcls, lg);
    k_rowstats<float><<<RR, 256, 0, stream>>>(lg, rmax, rsum);
    k_class<true><<<KCLS, 256, 0, stream>>>(nullptr, lg, rmax, rsum, boxes, per_scores, per_idx, hist1);
  }

  k_sel1<<<1, 1024, 0, stream>>>(hist1, sel);
  k_hist2<<<gFlat, 256, 0, stream>>>(per_scores, sel, hist2);
  k_sel2<<<1, 1024, 0, stream>>>(hist2, sel);
  k_compact<<<gFlat, 256, 0, stream>>>(per_scores, sel, deflist, tielist);
  k_final<<<1, 1024, 0, stream>>>(deflist, tielist, sel, per_idx, boxes, out);
}

// Round 6
// 710.812 us; speedup vs baseline: 1.4183x; 1.1625x over previous
//
#include <hip/hip_runtime.h>
#include <math.h>
#include <stdint.h>

#define RR 8192
#define DD 1024
#define KCLS 1203
#define KP 1204
#define KP2 1216   // padded logits/scores stride (MFMA path)
#define NB 1280    // padded B columns (10 tiles of 128)
#define MM 128
#define TOPKN 300
#define NFLAT (KCLS * MM)
#define NEGV (-1e9f)
#define SCLAMP 4.1351665567423563f

typedef __attribute__((ext_vector_type(8))) short bf16x8;
typedef __attribute__((ext_vector_type(4))) float f32x4;

__device__ __forceinline__ unsigned fmono(float f) {
  unsigned u = __float_as_uint(f);
  return (u & 0x80000000u) ? ~u : (u | 0x80000000u);
}
__device__ __forceinline__ float monof(unsigned u) {
  return __uint_as_float((u & 0x80000000u) ? (u ^ 0x80000000u) : ~u);
}
__device__ __forceinline__ float iou_f(float4 a, float4 b) {
  float areaA = (a.z - a.x) * (a.w - a.y);
  float areaB = (b.z - b.x) * (b.w - b.y);
  float lx = fmaxf(a.x, b.x), ly = fmaxf(a.y, b.y);
  float rx = fminf(a.z, b.z), ry = fminf(a.w, b.w);
  float w = fmaxf(rx - lx, 0.f), h = fmaxf(ry - ly, 0.f);
  float inter = w * h;
  return inter / (areaA + areaB - inter + 1e-6f);
}

__device__ __forceinline__ unsigned short bf16_rn(float x) {
  unsigned u = __float_as_uint(x);
  unsigned r = (u + 0x7FFFu + ((u >> 16) & 1u)) >> 16;
  return (unsigned short)r;
}
__device__ __forceinline__ float bf16f(unsigned short h) {
  return __uint_as_float(((unsigned)h) << 16);
}
// exact 3-way split: x = hi + mid + lo + eps, |eps| ~ 2^-25|x|
__device__ __forceinline__ void split3(float x, unsigned short& h, unsigned short& m2, unsigned short& l) {
  h = bf16_rn(x);
  float r1 = x - bf16f(h);
  m2 = bf16_rn(r1);
  float r2 = r1 - bf16f(m2);
  l = bf16_rn(r2);
}

// ---------------- split feat -> 3 bf16 planes [3][RR][DD] -----------------
__global__ __launch_bounds__(256) void k_split_feat(const float* __restrict__ feat,
                                                    unsigned short* __restrict__ Ap) {
  const size_t i4 = (size_t)blockIdx.x * 256 + threadIdx.x;  // float4 index
  float4 v = *(const float4*)&feat[i4 * 4];
  ushort4 h, m2, l;
  split3(v.x, h.x, m2.x, l.x);
  split3(v.y, h.y, m2.y, l.y);
  split3(v.z, h.z, m2.z, l.z);
  split3(v.w, h.w, m2.w, l.w);
  const size_t P = (size_t)RR * DD;
  *(ushort4*)&Ap[0 * P + i4 * 4] = h;
  *(ushort4*)&Ap[1 * P + i4 * 4] = m2;
  *(ushort4*)&Ap[2 * P + i4 * 4] = l;
}

// ---------------- split+transpose w_cls -> 3 bf16 planes Bt [3][NB][DD] -----------------
__global__ __launch_bounds__(256) void k_split_w(const float* __restrict__ wcls,
                                                 unsigned short* __restrict__ Btp) {
  __shared__ float st[64][65];
  const int c0 = blockIdx.x * 64, k0 = blockIdx.y * 64;
  const int tid = threadIdx.x;
  const int cc = tid & 63, kq = tid >> 6;
  for (int it = 0; it < 16; ++it) {
    int kl = it * 4 + kq;
    int c = c0 + cc;
    st[cc][kl] = (c < KP) ? wcls[(size_t)(k0 + kl) * KP + c] : 0.f;
  }
  __syncthreads();
  const int kk = tid & 63, cq = tid >> 6;
  const size_t P = (size_t)NB * DD;
  for (int it = 0; it < 16; ++it) {
    int cl = it * 4 + cq;
    float v = st[cl][kk];
    unsigned short h, m2, l;
    split3(v, h, m2, l);
    size_t off = (size_t)(c0 + cl) * DD + k0 + kk;
    Btp[0 * P + off] = h;
    Btp[1 * P + off] = m2;
    Btp[2 * P + off] = l;
  }
}

// ---------------- MFMA GEMM: logits = feat @ w_cls + b_cls (double out) -----------------
// 128x128 tile, BK=32, 8 waves (2Mx4N), wave=64x32, 16x16x32 bf16 MFMA, 6-term split.
// fp64 fold every 64 K -> logit error ~1.3e-7.
__global__ __launch_bounds__(512) void k_gemm_mfma(const unsigned short* __restrict__ Ap,
                                                   const unsigned short* __restrict__ Btp,
                                                   const float* __restrict__ bcls,
                                                   double* __restrict__ outlg) {
  __shared__ unsigned short As[3][128][40];  // padded: 80B rows -> 2-way bank conflict only
  __shared__ unsigned short Bs[3][128][40];
  const int tid = threadIdx.x;
  const int r0 = blockIdx.y * 128;
  const int c0 = blockIdx.x * 128;
  const int wid = tid >> 6, lane = tid & 63;
  const int wm = wid >> 2, wn = wid & 3;
  const int wrow = wm * 64, wcol = wn * 32;
  const int l15 = lane & 15, l4 = lane >> 4;

  f32x4 acc[4][2];
  double acc64[4][2][4];
#pragma unroll
  for (int mf = 0; mf < 4; ++mf)
#pragma unroll
    for (int nf = 0; nf < 2; ++nf) {
      acc[mf][nf] = (f32x4){0.f, 0.f, 0.f, 0.f};
#pragma unroll
      for (int q = 0; q < 4; ++q) acc64[mf][nf][q] = 0.0;
    }

  const size_t PA = (size_t)RR * DD;
  const size_t PB = (size_t)NB * DD;

  for (int kt = 0; kt < 32; ++kt) {
    __syncthreads();
#pragma unroll
    for (int it = 0; it < 3; ++it) {
      int c2 = it * 512 + tid;         // 0..1535 : 3 planes x 128 rows x 4 chunks
      int plane = c2 >> 9;
      int rr2 = (c2 >> 2) & 127;
      int jc = (c2 & 3) << 3;          // element offset 0,8,16,24
      const uint4 av = *(const uint4*)(Ap + (size_t)plane * PA + ((size_t)(r0 + rr2)) * DD + kt * 32 + jc);
      const uint4 bv = *(const uint4*)(Btp + (size_t)plane * PB + ((size_t)(c0 + rr2)) * DD + kt * 32 + jc);
      *(uint4*)&As[plane][rr2][jc] = av;
      *(uint4*)&Bs[plane][rr2][jc] = bv;
    }
    __syncthreads();

    bf16x8 bf[2][3];
#pragma unroll
    for (int nf = 0; nf < 2; ++nf)
#pragma unroll
      for (int p = 0; p < 3; ++p)
        bf[nf][p] = *(const bf16x8*)&Bs[p][wcol + nf * 16 + l15][l4 * 8];

#pragma unroll
    for (int mf = 0; mf < 4; ++mf) {
      bf16x8 a0 = *(const bf16x8*)&As[0][wrow + mf * 16 + l15][l4 * 8];
      bf16x8 a1 = *(const bf16x8*)&As[1][wrow + mf * 16 + l15][l4 * 8];
      bf16x8 a2 = *(const bf16x8*)&As[2][wrow + mf * 16 + l15][l4 * 8];
#pragma unroll
      for (int nf = 0; nf < 2; ++nf) {
        f32x4 a = acc[mf][nf];
        a = __builtin_amdgcn_mfma_f32_16x16x32_bf16(a0, bf[nf][0], a, 0, 0, 0);  // hh
        a = __builtin_amdgcn_mfma_f32_16x16x32_bf16(a0, bf[nf][1], a, 0, 0, 0);  // hm
        a = __builtin_amdgcn_mfma_f32_16x16x32_bf16(a1, bf[nf][0], a, 0, 0, 0);  // mh
        a = __builtin_amdgcn_mfma_f32_16x16x32_bf16(a0, bf[nf][2], a, 0, 0, 0);  // hl
        a = __builtin_amdgcn_mfma_f32_16x16x32_bf16(a2, bf[nf][0], a, 0, 0, 0);  // lh
        a = __builtin_amdgcn_mfma_f32_16x16x32_bf16(a1, bf[nf][1], a, 0, 0, 0);  // mm
        acc[mf][nf] = a;
      }
    }

    if (kt & 1) {  // fold into fp64 every 64 K
#pragma unroll
      for (int mf = 0; mf < 4; ++mf)
#pragma unroll
        for (int nf = 0; nf < 2; ++nf) {
#pragma unroll
          for (int q = 0; q < 4; ++q) acc64[mf][nf][q] += (double)acc[mf][nf][q];
          acc[mf][nf] = (f32x4){0.f, 0.f, 0.f, 0.f};
        }
    }
  }

#pragma unroll
  for (int mf = 0; mf < 4; ++mf)
#pragma unroll
    for (int nf = 0; nf < 2; ++nf) {
      int c = c0 + wcol + nf * 16 + l15;
      if (c < KP) {
#pragma unroll
        for (int q = 0; q < 4; ++q) {
          int r = r0 + wrow + mf * 16 + l4 * 4 + q;
          outlg[(size_t)r * KP2 + c] = acc64[mf][nf][q] + (double)bcls[c];
        }
      }
    }
}

// ---------------- fused per-row softmax (double) -> masked f32 scores [row][class] ---------
__global__ __launch_bounds__(256) void k_softmax(const double* __restrict__ lg,
                                                 float* __restrict__ scoresA) {
  const int r = blockIdx.x;
  const int tid = threadIdx.x;
  __shared__ double ex[KP];
  __shared__ double red[256];
  double m = -1e300;
  for (int c = tid; c < KP; c += 256) {
    double z = lg[(size_t)r * KP2 + c];
    ex[c] = z;
    m = fmax(m, z);
  }
  red[tid] = m;
  __syncthreads();
  for (int off = 128; off; off >>= 1) {
    if (tid < off) red[tid] = fmax(red[tid], red[tid + off]);
    __syncthreads();
  }
  m = red[0];
  __syncthreads();
  double s = 0.0;
  for (int c = tid; c < KP; c += 256) {
    double e = exp(ex[c] - m);
    ex[c] = e;
    s += e;
  }
  red[tid] = s;
  __syncthreads();
  for (int off = 128; off; off >>= 1) {
    if (tid < off) red[tid] += red[tid + off];
    __syncthreads();
  }
  s = red[0];
  __syncthreads();
  for (int c = tid; c < KCLS; c += 256) {
    float f = (float)(ex[c] / s);
    scoresA[(size_t)r * KP2 + c] = (f > 1e-4f) ? f : NEGV;
  }
}

// ---------------- f32 transpose: scoresA[row][class] -> scoresT[class][row] ---------------
__global__ __launch_bounds__(256) void k_transposeS(const float* __restrict__ scoresA,
                                                    float* __restrict__ scoresT) {
  __shared__ float st[64][65];
  const int c0 = blockIdx.x * 64, r0 = blockIdx.y * 64;
  const int tid = threadIdx.x;
  const int cc = tid & 63, rq = tid >> 6;
  for (int it = 0; it < 16; ++it) {
    int r = r0 + it * 4 + rq;
    int c = c0 + cc;
    if (c < KCLS) st[cc][it * 4 + rq] = scoresA[(size_t)r * KP2 + c];
  }
  __syncthreads();
  const int rr = tid & 63, cq = tid >> 6;
  for (int it = 0; it < 16; ++it) {
    int c = c0 + it * 4 + cq;
    if (c < KCLS) scoresT[(size_t)c * RR + r0 + rr] = st[it * 4 + cq][rr];
  }
}

// ---------------- legacy fp32-vector GEMM (fallback) -------------
template <typename ZT>
__global__ __launch_bounds__(256) void k_gemm(const float* __restrict__ feat,
                                              const float* __restrict__ wcls,
                                              const float* __restrict__ bcls,
                                              ZT* __restrict__ out) {
  __shared__ float As[16][64];
  __shared__ float Bs[16][64];
  const int tid = threadIdx.x;
  const int c0 = blockIdx.x * 64;
  const int r0 = blockIdx.y * 64;
  const int tx4 = (tid & 15) << 2;
  const int ty4 = (tid >> 4) << 2;
  const int arow = tid >> 2, akq = (tid & 3) << 2;
  const int bk = tid >> 4, bcol = (tid & 15) << 2;

  float fa[4][4];
  double da[4][4];
#pragma unroll
  for (int i = 0; i < 4; i++)
#pragma unroll
    for (int j = 0; j < 4; j++) { fa[i][j] = 0.f; da[i][j] = 0.0; }

  for (int kt = 0; kt < DD / 16; ++kt) {
    float4 av = *(const float4*)&feat[(size_t)(r0 + arow) * DD + kt * 16 + akq];
    float4 bv;
    {
      int gc = c0 + bcol;
      const float* wrow = &wcls[(size_t)(kt * 16 + bk) * KP];
      if (gc + 3 < KP) {
        bv = *(const float4*)&wrow[gc];
      } else {
        bv.x = (gc + 0 < KP) ? wrow[gc + 0] : 0.f;
        bv.y = (gc + 1 < KP) ? wrow[gc + 1] : 0.f;
        bv.z = (gc + 2 < KP) ? wrow[gc + 2] : 0.f;
        bv.w = (gc + 3 < KP) ? wrow[gc + 3] : 0.f;
      }
    }
    __syncthreads();
    As[akq + 0][arow] = av.x;
    As[akq + 1][arow] = av.y;
    As[akq + 2][arow] = av.z;
    As[akq + 3][arow] = av.w;
    *(float4*)&Bs[bk][bcol] = bv;
    __syncthreads();
#pragma unroll
    for (int k = 0; k < 16; ++k) {
      float4 a = *(const float4*)&As[k][ty4];
      float4 b = *(const float4*)&Bs[k][tx4];
      float ax[4] = {a.x, a.y, a.z, a.w};
      float bx[4] = {b.x, b.y, b.z, b.w};
#pragma unroll
      for (int i = 0; i < 4; i++)
#pragma unroll
        for (int j = 0; j < 4; j++) fa[i][j] = fmaf(ax[i], bx[j], fa[i][j]);
    }
#pragma unroll
    for (int i = 0; i < 4; i++)
#pragma unroll
      for (int j = 0; j < 4; j++) { da[i][j] += (double)fa[i][j]; fa[i][j] = 0.f; }
  }
#pragma unroll
  for (int i = 0; i < 4; i++) {
    int r = r0 + ty4 + i;
#pragma unroll
    for (int j = 0; j < 4; j++) {
      int c = c0 + tx4 + j;
      if (c < KP) out[(size_t)r * KP + c] = (ZT)(da[i][j] + (double)bcls[c]);
    }
  }
}

// ---------------- legacy rowstats (fallback) -----------------
template <typename ZT>
__global__ __launch_bounds__(256) void k_rowstats(const ZT* __restrict__ z,
                                                  double* __restrict__ rmax,
                                                  double* __restrict__ rsum) {
  const int r = blockIdx.x;
  const int tid = threadIdx.x;
  __shared__ double red[256];
  double m = -1e300;
  for (int c = tid; c < KP; c += 256) m = fmax(m, (double)z[(size_t)r * KP + c]);
  red[tid] = m;
  __syncthreads();
  for (int off = 128; off; off >>= 1) {
    if (tid < off) red[tid] = fmax(red[tid], red[tid + off]);
    __syncthreads();
  }
  m = red[0];
  __syncthreads();
  double s = 0.0;
  for (int c = tid; c < KP; c += 256) s += exp((double)z[(size_t)r * KP + c] - m);
  red[tid] = s;
  __syncthreads();
  for (int off = 128; off; off >>= 1) {
    if (tid < off) red[tid] += red[tid + off];
    __syncthreads();
  }
  if (tid == 0) { rmax[r] = m; rsum[r] = red[0]; }
}

// ---------------- legacy masked scores transpose (fallback) -----------------
template <typename ZT>
__global__ __launch_bounds__(256) void k_scores(const ZT* __restrict__ z,
                                                const double* __restrict__ rmax,
                                                const double* __restrict__ rsum,
                                                float* __restrict__ scoresT) {
  __shared__ float st[64][65];
  const int c0 = blockIdx.x * 64, r0 = blockIdx.y * 64;
  const int tid = threadIdx.x;
  const int cc = tid & 63, rq = tid >> 6;
  for (int it = 0; it < 16; ++it) {
    int r = r0 + it * 4 + rq;
    int c = c0 + cc;
    if (c < KCLS) {
      double zz = (double)z[(size_t)r * KP + c];
      double sc = exp(zz - rmax[r]) / rsum[r];
      float f = (float)sc;
      st[cc][it * 4 + rq] = (f > 1e-4f) ? f : NEGV;
    }
  }
  __syncthreads();
  const int rr = tid & 63, cq = tid >> 6;
  for (int it = 0; it < 16; ++it) {
    int c = c0 + it * 4 + cq;
    if (c < KCLS) scoresT[(size_t)c * RR + r0 + rr] = st[it * 4 + cq][rr];
  }
}

// ---------------- box deltas (GEMV) + apply + clip -----------------
__global__ __launch_bounds__(256) void k_boxes(const float* __restrict__ feat,
                                               const float* __restrict__ wbox,
                                               const float* __restrict__ bbox,
                                               const float* __restrict__ props,
                                               float* __restrict__ boxes) {
  const int wid = threadIdx.x >> 6, lane = threadIdx.x & 63;
  const int r = blockIdx.x * 4 + wid;
  float p0 = 0, p1 = 0, p2 = 0, p3 = 0;
  for (int k = lane; k < DD; k += 64) {
    float f = feat[(size_t)r * DD + k];
    float4 w = *(const float4*)&wbox[k * 4];
    p0 = fmaf(f, w.x, p0);
    p1 = fmaf(f, w.y, p1);
    p2 = fmaf(f, w.z, p2);
    p3 = fmaf(f, w.w, p3);
  }
  for (int off = 32; off; off >>= 1) {
    p0 += __shfl_down(p0, off);
    p1 += __shfl_down(p1, off);
    p2 += __shfl_down(p2, off);
    p3 += __shfl_down(p3, off);
  }
  if (lane == 0) {
    p0 += bbox[0]; p1 += bbox[1]; p2 += bbox[2]; p3 += bbox[3];
    float4 pr = *(const float4*)&props[r * 4];
    float w = pr.z - pr.x, h = pr.w - pr.y;
    float cx = pr.x + 0.5f * w, cy = pr.y + 0.5f * h;
    float dx = p0 / 10.f, dy = p1 / 10.f;
    float dw = fminf(p2 / 5.f, SCLAMP), dh = fminf(p3 / 5.f, SCLAMP);
    float pcx = dx * w + cx, pcy = dy * h + cy;
    float pw = expf(dw) * w, ph = expf(dh) * h;
    float x1 = pcx - 0.5f * pw, y1 = pcy - 0.5f * ph;
    float x2 = pcx + 0.5f * pw, y2 = pcy + 0.5f * ph;
    x1 = fminf(fmaxf(x1, 0.f), 1333.f);
    x2 = fminf(fmaxf(x2, 0.f), 1333.f);
    y1 = fminf(fmaxf(y1, 0.f), 800.f);
    y2 = fminf(fmaxf(y2, 0.f), 800.f);
    *(float4*)&boxes[r * 4] = make_float4(x1, y1, x2, y2);
  }
}

// ---------------- per-class exact top-128 + NMS; also feed global L1 histogram -----------------
template <bool DIRECT>
__global__ __launch_bounds__(256) void k_class(const float* __restrict__ scoresT,
                                               const float* __restrict__ lgf,
                                               const double* __restrict__ rmax,
                                               const double* __restrict__ rsum,
                                               const float* __restrict__ boxes,
                                               float* __restrict__ per_scores,
                                               int* __restrict__ per_idx,
                                               unsigned* __restrict__ hist1) {
  const int c = blockIdx.x, tid = threadIdx.x;
  __shared__ float sval[RR];
  __shared__ unsigned hist[256];
  __shared__ unsigned cum[256];
  __shared__ uint64_t skey[MM];
  __shared__ float4 sbox[MM];
  __shared__ int skeep[MM];
  __shared__ uint64_t s_prefix;
  __shared__ int s_need, s_cnt, s_supp;

  for (int r2 = tid; r2 < RR; r2 += 256) {
    float s;
    if (DIRECT) {
      double sc = exp((double)lgf[(size_t)r2 * KP + c] - rmax[r2]) / rsum[r2];
      float f = (float)sc;
      s = (f > 1e-4f) ? f : NEGV;
    } else {
      s = scoresT[(size_t)c * RR + r2];
    }
    sval[r2] = s;
  }
  if (tid == 0) { s_prefix = 0; s_need = MM; s_cnt = 0; }
  if (tid < MM) skey[tid] = 0;
  __syncthreads();

  for (int pass = 0; pass < 6; ++pass) {
    const int shift = 40 - 8 * pass;
    hist[tid] = 0;
    __syncthreads();
    uint64_t pre = s_prefix;
    int nd = s_need;
    for (int r2 = tid; r2 < RR; r2 += 256) {
      uint64_t key = ((uint64_t)fmono(sval[r2]) << 13) | (uint64_t)(8191 - r2);
      if ((key >> (shift + 8)) == (pre >> (shift + 8)))
        atomicAdd(&hist[(unsigned)(key >> shift) & 255u], 1u);
    }
    __syncthreads();
    cum[tid] = hist[tid];
    __syncthreads();
    for (int off = 1; off < 256; off <<= 1) {
      unsigned add = (tid + off < 256) ? cum[tid + off] : 0u;
      __syncthreads();
      cum[tid] += add;
      __syncthreads();
    }
    unsigned mycum = cum[tid];
    unsigned nxt = (tid < 255) ? cum[tid + 1] : 0u;
    if ((int)mycum >= nd && (int)nxt < nd) {
      s_prefix = pre | ((uint64_t)tid << shift);
      s_need = nd - (int)nxt;
    }
    __syncthreads();
  }
  const uint64_t kthr = s_prefix;
  for (int r2 = tid; r2 < RR; r2 += 256) {
    uint64_t key = ((uint64_t)fmono(sval[r2]) << 13) | (uint64_t)(8191 - r2);
    if (key >= kthr) {
      int p = atomicAdd(&s_cnt, 1);
      if (p < MM) skey[p] = key;
    }
  }
  __syncthreads();
  for (int kk2 = 2; kk2 <= MM; kk2 <<= 1)
    for (int j = kk2 >> 1; j > 0; j >>= 1) {
      __syncthreads();
      if (tid < MM) {
        int ixj = tid ^ j;
        if (ixj > tid) {
          uint64_t a = skey[tid], b = skey[ixj];
          bool desc = ((tid & kk2) == 0);
          if (desc ? (a < b) : (a > b)) { skey[tid] = b; skey[ixj] = a; }
        }
      }
    }
  __syncthreads();
  float myval = 0.f;
  int myidx = 0;
  bool valid = false;
  float4 mybox = make_float4(0, 0, 0, 0);
  if (tid < MM) {
    uint64_t key = skey[tid];
    myidx = 8191 - (int)(key & 0x1FFFu);
    myval = monof((unsigned)(key >> 13));
    valid = myval > -5e8f;
    mybox = *(const float4*)&boxes[myidx * 4];
    sbox[tid] = mybox;
    skeep[tid] = 0;
  }
  __syncthreads();
  for (int i = 0; i < MM; ++i) {
    if (tid == 0) s_supp = 0;
    __syncthreads();
    if (tid < i && skeep[tid]) {
      if (iou_f(mybox, sbox[i]) > 0.5f) s_supp = 1;
    }
    __syncthreads();
    if (tid == i) skeep[i] = (valid && !s_supp) ? 1 : 0;
  }
  __syncthreads();
  if (tid < MM) {
    per_scores[(size_t)c * MM + tid] = skeep[tid] ? myval : NEGV;
    per_idx[(size_t)c * MM + tid] = myidx;
    if (skeep[tid]) atomicAdd(&hist1[fmono(myval) >> 16], 1u);
  }
}

// ---------------- global top-300: two-level radix threshold + compact + small sort ----------
__global__ __launch_bounds__(1024) void k_sel1(const unsigned* __restrict__ hist, int* __restrict__ sel) {
  __shared__ unsigned red[1024];
  const int t = threadIdx.x;
  unsigned s = 0;
#pragma unroll 8
  for (int i = 0; i < 64; i++) s += hist[t * 64 + i];
  red[t] = s;
  __syncthreads();
  for (int off = 1; off < 1024; off <<= 1) {
    unsigned add = (t + off < 1024) ? red[t + off] : 0u;
    __syncthreads();
    red[t] += add;
    __syncthreads();
  }
  unsigned above = (t < 1023) ? red[t + 1] : 0u;
  if (red[t] >= (unsigned)TOPKN && above < (unsigned)TOPKN) {
    unsigned run = above;
    for (int b = 63; b >= 0; --b) {
      unsigned cb = hist[t * 64 + b];
      if (run < (unsigned)TOPKN && run + cb >= (unsigned)TOPKN) {
        sel[0] = t * 64 + b;
        sel[1] = (int)((unsigned)TOPKN - run);
      }
      run += cb;
    }
  }
}

__global__ __launch_bounds__(256) void k_hist2(const float* __restrict__ per_scores,
                                               const int* __restrict__ sel,
                                               unsigned* __restrict__ hist2) {
  const int f = blockIdx.x * 256 + threadIdx.x;
  if (f >= NFLAT) return;
  const unsigned p16 = (unsigned)sel[0];
  unsigned u = fmono(per_scores[f]);
  if ((u >> 16) == p16) atomicAdd(&hist2[u & 0xFFFFu], 1u);
}

__global__ __launch_bounds__(1024) void k_sel2(const unsigned* __restrict__ hist, int* __restrict__ sel) {
  __shared__ unsigned red[1024];
  __shared__ unsigned sneed, sp16;
  const int t = threadIdx.x;
  if (t == 0) { sneed = (unsigned)sel[1]; sp16 = (unsigned)sel[0]; }
  __syncthreads();
  const unsigned NEED = sneed;
  unsigned s = 0;
#pragma unroll 8
  for (int i = 0; i < 64; i++) s += hist[t * 64 + i];
  red[t] = s;
  __syncthreads();
  for (int off = 1; off < 1024; off <<= 1) {
    unsigned add = (t + off < 1024) ? red[t + off] : 0u;
    __syncthreads();
    red[t] += add;
    __syncthreads();
  }
  unsigned above = (t < 1023) ? red[t + 1] : 0u;
  if (red[t] >= NEED && above < NEED) {
    unsigned run = above;
    for (int b = 63; b >= 0; --b) {
      unsigned cb = hist[t * 64 + b];
      if (run < NEED && run + cb >= NEED) {
        sel[2] = (int)((sp16 << 16) | (unsigned)(t * 64 + b));
      }
      run += cb;
    }
  }
}

__global__ __launch_bounds__(256) void k_compact(const float* __restrict__ per_scores,
                                                 int* __restrict__ sel,
                                                 uint64_t* __restrict__ deflist,
                                                 uint64_t* __restrict__ tielist) {
  const int f = blockIdx.x * 256 + threadIdx.x;
  if (f >= NFLAT) return;
  const unsigned v32 = (unsigned)sel[2];
  unsigned u = fmono(per_scores[f]);
  if (u < v32) return;
  uint64_t key = ((uint64_t)u << 18) | (uint64_t)(262143 - f);
  if (u > v32) {
    int p = atomicAdd(&sel[4], 1);
    if (p < 512) deflist[p] = key;
  } else {
    int p = atomicAdd(&sel[5], 1);
    if (p < 512) tielist[p] = key;
  }
}

__global__ __launch_bounds__(1024) void k_final(const uint64_t* __restrict__ deflist,
                                                const uint64_t* __restrict__ tielist,
                                                const int* __restrict__ sel,
                                                const int* __restrict__ per_idx,
                                                const float* __restrict__ boxes,
                                                float* __restrict__ out) {
  __shared__ uint64_t skey[1024];
  const int t = threadIdx.x;
  const int n0 = min(sel[4], 512);
  const int n1 = min(sel[5], 512);
  uint64_t k = 0;
  if (t < n0) k = deflist[t];
  else if (t - n0 < n1) k = tielist[t - n0];
  skey[t] = k;
  __syncthreads();
  for (int kk2 = 2; kk2 <= 1024; kk2 <<= 1)
    for (int j = kk2 >> 1; j > 0; j >>= 1) {
      __syncthreads();
      int ixj = t ^ j;
      if (ixj > t) {
        uint64_t a = skey[t], b = skey[ixj];
        bool desc = ((t & kk2) == 0);
        if (desc ? (a < b) : (a > b)) { skey[t] = b; skey[ixj] = a; }
      }
    }
  __syncthreads();
  if (t < TOPKN) {
    uint64_t key = skey[t];
    int f = 262143 - (int)(key & 0x3FFFFu);
    float val = monof((unsigned)(key >> 18));
    int cls = f >> 7;
    int prop = per_idx[f];
    float4 b = *(const float4*)&boxes[prop * 4];
    float* o = &out[t * 6];
    o[0] = b.x; o[1] = b.y; o[2] = b.z; o[3] = b.w;
    o[4] = val; o[5] = (float)cls;
  }
}

extern "C" void kernel_launch(void* const* d_in, const int* in_sizes, int n_in,
                              void* d_out, int out_size, void* d_ws, size_t ws_size,
                              hipStream_t stream) {
  const float* feat = (const float*)d_in[0];
  const float* props = (const float*)d_in[1];
  const float* wcls = (const float*)d_in[2];
  const float* bcls = (const float*)d_in[3];
  const float* wbox = (const float*)d_in[4];
  const float* bbox = (const float*)d_in[5];
  float* out = (float*)d_out;
  char* ws = (char*)d_ws;

  size_t o = 0;
  auto al = [&](size_t b) { size_t cur = o; o += (b + 255) & ~(size_t)255; return cur; };
  const size_t o_boxes = al((size_t)RR * 4 * 4);
  const size_t o_ps = al((size_t)KCLS * MM * 4);
  const size_t o_pi = al((size_t)KCLS * MM * 4);
  const size_t o_rmax = al((size_t)RR * 8);
  const size_t o_rsum = al((size_t)RR * 8);
  const size_t o_hist1 = al((size_t)65536 * 4);
  const size_t o_hist2 = al((size_t)65536 * 4);
  const size_t o_sel = al((size_t)256);
  const size_t o_def = al((size_t)512 * 8);
  const size_t o_tie = al((size_t)512 * 8);
  const size_t fixed_end = o;

  float* boxes = (float*)(ws + o_boxes);
  float* per_scores = (float*)(ws + o_ps);
  int* per_idx = (int*)(ws + o_pi);
  double* rmax = (double*)(ws + o_rmax);
  double* rsum = (double*)(ws + o_rsum);
  unsigned* hist1 = (unsigned*)(ws + o_hist1);
  unsigned* hist2 = (unsigned*)(ws + o_hist2);
  int* sel = (int*)(ws + o_sel);
  uint64_t* deflist = (uint64_t*)(ws + o_def);
  uint64_t* tielist = (uint64_t*)(ws + o_tie);

  // MFMA-path layout (with aliasing): A-planes (also scoresA), Bt-planes, logits (also scoresT)
  const size_t sz_A3 = ((size_t)3 * RR * DD * 2 + 255) & ~(size_t)255;      // 50.3 MB
  const size_t sz_Bt = ((size_t)3 * NB * DD * 2 + 255) & ~(size_t)255;      // 7.9 MB
  const size_t sz_lg2 = ((size_t)RR * KP2 * 8 + 255) & ~(size_t)255;        // 79.7 MB
  const size_t needM = fixed_end + sz_A3 + sz_Bt + sz_lg2;

  const size_t sz_scT = ((size_t)KCLS * RR * 4 + 255) & ~(size_t)255;
  const size_t sz_lgD = ((size_t)RR * KP * 8 + 255) & ~(size_t)255;
  const size_t sz_lgF = ((size_t)RR * KP * 4 + 255) & ~(size_t)255;

  const bool pathM = ws_size >= needM;
  const bool pathA = !pathM && ws_size >= fixed_end + sz_scT + sz_lgD;
  const bool pathB = !pathM && !pathA && ws_size >= fixed_end + sz_scT + sz_lgF;

  const int gFlat = (NFLAT + 255) / 256;

  hipMemsetAsync(ws + o_hist1, 0, (o_sel - o_hist1) + 256, stream);

  k_boxes<<<RR / 4, 256, 0, stream>>>(feat, wbox, bbox, props, boxes);

  if (pathM) {
    unsigned short* Ap = (unsigned short*)(ws + fixed_end);
    unsigned short* Btp = (unsigned short*)(ws + fixed_end + sz_A3);
    double* lg = (double*)(ws + fixed_end + sz_A3 + sz_Bt);
    float* scoresA = (float*)(ws + fixed_end);                 // aliases Ap (dead after GEMM)
    float* scoresT = (float*)(ws + fixed_end + sz_A3 + sz_Bt); // aliases lg (dead after softmax)

    k_split_feat<<<(RR * DD / 4) / 256, 256, 0, stream>>>(feat, Ap);
    k_split_w<<<dim3(NB / 64, DD / 64), 256, 0, stream>>>(wcls, Btp);
    k_gemm_mfma<<<dim3(NB / 128, RR / 128), 512, 0, stream>>>(Ap, Btp, bcls, lg);
    k_softmax<<<RR, 256, 0, stream>>>(lg, scoresA);
    k_transposeS<<<dim3(KP2 / 64, RR / 64), 256, 0, stream>>>(scoresA, scoresT);
    k_class<false><<<KCLS, 256, 0, stream>>>(scoresT, nullptr, rmax, rsum, boxes, per_scores, per_idx, hist1);
  } else if (pathA) {
    float* scoresT = (float*)(ws + fixed_end);
    double* lg = (double*)(ws + fixed_end + sz_scT);
    k_gemm<double><<<dim3(19, 128), 256, 0, stream>>>(feat, wcls, bcls, lg);
    k_rowstats<double><<<RR, 256, 0, stream>>>(lg, rmax, rsum);
    k_scores<double><<<dim3(19, 128), 256, 0, stream>>>(lg, rmax, rsum, scoresT);
    k_class<false><<<KCLS, 256, 0, stream>>>(scoresT, nullptr, rmax, rsum, boxes, per_scores, per_idx, hist1);
  } else if (pathB) {
    float* scoresT = (float*)(ws + fixed_end);
    float* lg = (float*)(ws + fixed_end + sz_scT);
    k_gemm<float><<<dim3(19, 128), 256, 0, stream>>>(feat, wcls, bcls, lg);
    k_rowstats<float><<<RR, 256, 0, stream>>>(lg, rmax, rsum);
    k_scores<float><<<dim3(19, 128), 256, 0, stream>>>(lg, rmax, rsum, scoresT);
    k_class<false><<<KCLS, 256, 0, stream>>>(scoresT, nullptr, rmax, rsum, boxes, per_scores, per_idx, hist1);
  } else {
    float* lg = (float*)(ws + fixed_end);
    k_gemm<float><<<dim3(19, 128), 256, 0, stream>>>(feat, wcls, bcls, lg);
    k_rowstats<float><<<RR, 256, 0, stream>>>(lg, rmax, rsum);
    k_class<true><<<KCLS, 256, 0, stream>>>(nullptr, lg, rmax, rsum, boxes, per_scores, per_idx, hist1);
  }

  k_sel1<<<1, 1024, 0, stream>>>(hist1, sel);
  k_hist2<<<gFlat, 256, 0, stream>>>(per_scores, sel, hist2);
  k_sel2<<<1, 1024, 0, stream>>>(hist2, sel);
  k_compact<<<gFlat, 256, 0, stream>>>(per_scores, sel, deflist, tielist);
  k_final<<<1, 1024, 0, stream>>>(deflist, tielist, sel, per_idx, boxes, out);
}

// Round 7
// 633.385 us; speedup vs baseline: 1.5917x; 1.1222x over previous
//
#include <hip/hip_runtime.h>
#include <math.h>
#include <stdint.h>

#define RR 8192
#define DD 1024
#define KCLS 1203
#define KP 1204
#define KP2 1216   // padded logits/scores stride (MFMA path)
#define NB 1280    // padded B columns (10 tiles of 128)
#define MM 128
#define TOPKN 300
#define NFLAT (KCLS * MM)
#define NEGV (-1e9f)
#define SCLAMP 4.1351665567423563f

typedef __attribute__((ext_vector_type(8))) short bf16x8;
typedef __attribute__((ext_vector_type(4))) float f32x4;

__device__ __forceinline__ unsigned fmono(float f) {
  unsigned u = __float_as_uint(f);
  return (u & 0x80000000u) ? ~u : (u | 0x80000000u);
}
__device__ __forceinline__ float monof(unsigned u) {
  return __uint_as_float((u & 0x80000000u) ? (u ^ 0x80000000u) : ~u);
}
__device__ __forceinline__ float iou_f(float4 a, float4 b) {
  float areaA = (a.z - a.x) * (a.w - a.y);
  float areaB = (b.z - b.x) * (b.w - b.y);
  float lx = fmaxf(a.x, b.x), ly = fmaxf(a.y, b.y);
  float rx = fminf(a.z, b.z), ry = fminf(a.w, b.w);
  float w = fmaxf(rx - lx, 0.f), h = fmaxf(ry - ly, 0.f);
  float inter = w * h;
  return inter / (areaA + areaB - inter + 1e-6f);
}

__device__ __forceinline__ unsigned short bf16_rn(float x) {
  unsigned u = __float_as_uint(x);
  unsigned r = (u + 0x7FFFu + ((u >> 16) & 1u)) >> 16;
  return (unsigned short)r;
}
__device__ __forceinline__ float bf16f(unsigned short h) {
  return __uint_as_float(((unsigned)h) << 16);
}
// exact 3-way split: x = hi + mid + lo + eps, |eps| ~ 2^-25|x|
__device__ __forceinline__ void split3(float x, unsigned short& h, unsigned short& m2, unsigned short& l) {
  h = bf16_rn(x);
  float r1 = x - bf16f(h);
  m2 = bf16_rn(r1);
  float r2 = r1 - bf16f(m2);
  l = bf16_rn(r2);
}

// ---------------- split feat -> 3 bf16 planes [3][RR][DD] -----------------
__global__ __launch_bounds__(256) void k_split_feat(const float* __restrict__ feat,
                                                    unsigned short* __restrict__ Ap) {
  const size_t i4 = (size_t)blockIdx.x * 256 + threadIdx.x;  // float4 index
  float4 v = *(const float4*)&feat[i4 * 4];
  ushort4 h, m2, l;
  split3(v.x, h.x, m2.x, l.x);
  split3(v.y, h.y, m2.y, l.y);
  split3(v.z, h.z, m2.z, l.z);
  split3(v.w, h.w, m2.w, l.w);
  const size_t P = (size_t)RR * DD;
  *(ushort4*)&Ap[0 * P + i4 * 4] = h;
  *(ushort4*)&Ap[1 * P + i4 * 4] = m2;
  *(ushort4*)&Ap[2 * P + i4 * 4] = l;
}

// ---------------- split+transpose w_cls -> 3 bf16 planes Bt [3][NB][DD] -----------------
__global__ __launch_bounds__(256) void k_split_w(const float* __restrict__ wcls,
                                                 unsigned short* __restrict__ Btp) {
  __shared__ float st[64][65];
  const int c0 = blockIdx.x * 64, k0 = blockIdx.y * 64;
  const int tid = threadIdx.x;
  const int cc = tid & 63, kq = tid >> 6;
  for (int it = 0; it < 16; ++it) {
    int kl = it * 4 + kq;
    int c = c0 + cc;
    st[cc][kl] = (c < KP) ? wcls[(size_t)(k0 + kl) * KP + c] : 0.f;
  }
  __syncthreads();
  const int kk = tid & 63, cq = tid >> 6;
  const size_t P = (size_t)NB * DD;
  for (int it = 0; it < 16; ++it) {
    int cl = it * 4 + cq;
    float v = st[cl][kk];
    unsigned short h, m2, l;
    split3(v, h, m2, l);
    size_t off = (size_t)(c0 + cl) * DD + k0 + kk;
    Btp[0 * P + off] = h;
    Btp[1 * P + off] = m2;
    Btp[2 * P + off] = l;
  }
}

// ---------------- MFMA GEMM: logits = feat @ w_cls + b_cls (double out) -----------------
// 128x128 tile, BK=32, 8 waves (2Mx4N), wave=64x32, 16x16x32 bf16 MFMA, 6-term split.
// fp64 fold every 64 K -> logit error ~1.3e-7.
__global__ __launch_bounds__(512) void k_gemm_mfma(const unsigned short* __restrict__ Ap,
                                                   const unsigned short* __restrict__ Btp,
                                                   const float* __restrict__ bcls,
                                                   double* __restrict__ outlg) {
  __shared__ unsigned short As[3][128][40];  // padded: 80B rows -> 2-way bank conflict only
  __shared__ unsigned short Bs[3][128][40];
  const int tid = threadIdx.x;
  const int r0 = blockIdx.y * 128;
  const int c0 = blockIdx.x * 128;
  const int wid = tid >> 6, lane = tid & 63;
  const int wm = wid >> 2, wn = wid & 3;
  const int wrow = wm * 64, wcol = wn * 32;
  const int l15 = lane & 15, l4 = lane >> 4;

  f32x4 acc[4][2];
  double acc64[4][2][4];
#pragma unroll
  for (int mf = 0; mf < 4; ++mf)
#pragma unroll
    for (int nf = 0; nf < 2; ++nf) {
      acc[mf][nf] = (f32x4){0.f, 0.f, 0.f, 0.f};
#pragma unroll
      for (int q = 0; q < 4; ++q) acc64[mf][nf][q] = 0.0;
    }

  const size_t PA = (size_t)RR * DD;
  const size_t PB = (size_t)NB * DD;

  for (int kt = 0; kt < 32; ++kt) {
    __syncthreads();
#pragma unroll
    for (int it = 0; it < 3; ++it) {
      int c2 = it * 512 + tid;         // 0..1535 : 3 planes x 128 rows x 4 chunks
      int plane = c2 >> 9;
      int rr2 = (c2 >> 2) & 127;
      int jc = (c2 & 3) << 3;          // element offset 0,8,16,24
      const uint4 av = *(const uint4*)(Ap + (size_t)plane * PA + ((size_t)(r0 + rr2)) * DD + kt * 32 + jc);
      const uint4 bv = *(const uint4*)(Btp + (size_t)plane * PB + ((size_t)(c0 + rr2)) * DD + kt * 32 + jc);
      *(uint4*)&As[plane][rr2][jc] = av;
      *(uint4*)&Bs[plane][rr2][jc] = bv;
    }
    __syncthreads();

    bf16x8 bf[2][3];
#pragma unroll
    for (int nf = 0; nf < 2; ++nf)
#pragma unroll
      for (int p = 0; p < 3; ++p)
        bf[nf][p] = *(const bf16x8*)&Bs[p][wcol + nf * 16 + l15][l4 * 8];

#pragma unroll
    for (int mf = 0; mf < 4; ++mf) {
      bf16x8 a0 = *(const bf16x8*)&As[0][wrow + mf * 16 + l15][l4 * 8];
      bf16x8 a1 = *(const bf16x8*)&As[1][wrow + mf * 16 + l15][l4 * 8];
      bf16x8 a2 = *(const bf16x8*)&As[2][wrow + mf * 16 + l15][l4 * 8];
#pragma unroll
      for (int nf = 0; nf < 2; ++nf) {
        f32x4 a = acc[mf][nf];
        a = __builtin_amdgcn_mfma_f32_16x16x32_bf16(a0, bf[nf][0], a, 0, 0, 0);  // hh
        a = __builtin_amdgcn_mfma_f32_16x16x32_bf16(a0, bf[nf][1], a, 0, 0, 0);  // hm
        a = __builtin_amdgcn_mfma_f32_16x16x32_bf16(a1, bf[nf][0], a, 0, 0, 0);  // mh
        a = __builtin_amdgcn_mfma_f32_16x16x32_bf16(a0, bf[nf][2], a, 0, 0, 0);  // hl
        a = __builtin_amdgcn_mfma_f32_16x16x32_bf16(a2, bf[nf][0], a, 0, 0, 0);  // lh
        a = __builtin_amdgcn_mfma_f32_16x16x32_bf16(a1, bf[nf][1], a, 0, 0, 0);  // mm
        acc[mf][nf] = a;
      }
    }

    if (kt & 1) {  // fold into fp64 every 64 K
#pragma unroll
      for (int mf = 0; mf < 4; ++mf)
#pragma unroll
        for (int nf = 0; nf < 2; ++nf) {
#pragma unroll
          for (int q = 0; q < 4; ++q) acc64[mf][nf][q] += (double)acc[mf][nf][q];
          acc[mf][nf] = (f32x4){0.f, 0.f, 0.f, 0.f};
        }
    }
  }

#pragma unroll
  for (int mf = 0; mf < 4; ++mf)
#pragma unroll
    for (int nf = 0; nf < 2; ++nf) {
      int c = c0 + wcol + nf * 16 + l15;
      if (c < KP) {
#pragma unroll
        for (int q = 0; q < 4; ++q) {
          int r = r0 + wrow + mf * 16 + l4 * 4 + q;
          outlg[(size_t)r * KP2 + c] = acc64[mf][nf][q] + (double)bcls[c];
        }
      }
    }
}

// ---------------- fused per-row softmax (double) -> masked f32 scores [row][class] ---------
__global__ __launch_bounds__(256) void k_softmax(const double* __restrict__ lg,
                                                 float* __restrict__ scoresA) {
  const int r = blockIdx.x;
  const int tid = threadIdx.x;
  __shared__ double ex[KP];
  __shared__ double red[256];
  double m = -1e300;
  for (int c = tid; c < KP; c += 256) {
    double z = lg[(size_t)r * KP2 + c];
    ex[c] = z;
    m = fmax(m, z);
  }
  red[tid] = m;
  __syncthreads();
  for (int off = 128; off; off >>= 1) {
    if (tid < off) red[tid] = fmax(red[tid], red[tid + off]);
    __syncthreads();
  }
  m = red[0];
  __syncthreads();
  double s = 0.0;
  for (int c = tid; c < KP; c += 256) {
    double e = exp(ex[c] - m);
    ex[c] = e;
    s += e;
  }
  red[tid] = s;
  __syncthreads();
  for (int off = 128; off; off >>= 1) {
    if (tid < off) red[tid] += red[tid + off];
    __syncthreads();
  }
  s = red[0];
  __syncthreads();
  for (int c = tid; c < KCLS; c += 256) {
    float f = (float)(ex[c] / s);
    scoresA[(size_t)r * KP2 + c] = (f > 1e-4f) ? f : NEGV;
  }
}

// ---------------- f32 transpose: scoresA[row][class] -> scoresT[class][row] ---------------
__global__ __launch_bounds__(256) void k_transposeS(const float* __restrict__ scoresA,
                                                    float* __restrict__ scoresT) {
  __shared__ float st[64][65];
  const int c0 = blockIdx.x * 64, r0 = blockIdx.y * 64;
  const int tid = threadIdx.x;
  const int cc = tid & 63, rq = tid >> 6;
  for (int it = 0; it < 16; ++it) {
    int r = r0 + it * 4 + rq;
    int c = c0 + cc;
    if (c < KCLS) st[cc][it * 4 + rq] = scoresA[(size_t)r * KP2 + c];
  }
  __syncthreads();
  const int rr = tid & 63, cq = tid >> 6;
  for (int it = 0; it < 16; ++it) {
    int c = c0 + it * 4 + cq;
    if (c < KCLS) scoresT[(size_t)c * RR + r0 + rr] = st[it * 4 + cq][rr];
  }
}

// ---------------- legacy fp32-vector GEMM (fallback) -------------
template <typename ZT>
__global__ __launch_bounds__(256) void k_gemm(const float* __restrict__ feat,
                                              const float* __restrict__ wcls,
                                              const float* __restrict__ bcls,
                                              ZT* __restrict__ out) {
  __shared__ float As[16][64];
  __shared__ float Bs[16][64];
  const int tid = threadIdx.x;
  const int c0 = blockIdx.x * 64;
  const int r0 = blockIdx.y * 64;
  const int tx4 = (tid & 15) << 2;
  const int ty4 = (tid >> 4) << 2;
  const int arow = tid >> 2, akq = (tid & 3) << 2;
  const int bk = tid >> 4, bcol = (tid & 15) << 2;

  float fa[4][4];
  double da[4][4];
#pragma unroll
  for (int i = 0; i < 4; i++)
#pragma unroll
    for (int j = 0; j < 4; j++) { fa[i][j] = 0.f; da[i][j] = 0.0; }

  for (int kt = 0; kt < DD / 16; ++kt) {
    float4 av = *(const float4*)&feat[(size_t)(r0 + arow) * DD + kt * 16 + akq];
    float4 bv;
    {
      int gc = c0 + bcol;
      const float* wrow = &wcls[(size_t)(kt * 16 + bk) * KP];
      if (gc + 3 < KP) {
        bv = *(const float4*)&wrow[gc];
      } else {
        bv.x = (gc + 0 < KP) ? wrow[gc + 0] : 0.f;
        bv.y = (gc + 1 < KP) ? wrow[gc + 1] : 0.f;
        bv.z = (gc + 2 < KP) ? wrow[gc + 2] : 0.f;
        bv.w = (gc + 3 < KP) ? wrow[gc + 3] : 0.f;
      }
    }
    __syncthreads();
    As[akq + 0][arow] = av.x;
    As[akq + 1][arow] = av.y;
    As[akq + 2][arow] = av.z;
    As[akq + 3][arow] = av.w;
    *(float4*)&Bs[bk][bcol] = bv;
    __syncthreads();
#pragma unroll
    for (int k = 0; k < 16; ++k) {
      float4 a = *(const float4*)&As[k][ty4];
      float4 b = *(const float4*)&Bs[k][tx4];
      float ax[4] = {a.x, a.y, a.z, a.w};
      float bx[4] = {b.x, b.y, b.z, b.w};
#pragma unroll
      for (int i = 0; i < 4; i++)
#pragma unroll
        for (int j = 0; j < 4; j++) fa[i][j] = fmaf(ax[i], bx[j], fa[i][j]);
    }
#pragma unroll
    for (int i = 0; i < 4; i++)
#pragma unroll
      for (int j = 0; j < 4; j++) { da[i][j] += (double)fa[i][j]; fa[i][j] = 0.f; }
  }
#pragma unroll
  for (int i = 0; i < 4; i++) {
    int r = r0 + ty4 + i;
#pragma unroll
    for (int j = 0; j < 4; j++) {
      int c = c0 + tx4 + j;
      if (c < KP) out[(size_t)r * KP + c] = (ZT)(da[i][j] + (double)bcls[c]);
    }
  }
}

// ---------------- legacy rowstats (fallback) -----------------
template <typename ZT>
__global__ __launch_bounds__(256) void k_rowstats(const ZT* __restrict__ z,
                                                  double* __restrict__ rmax,
                                                  double* __restrict__ rsum) {
  const int r = blockIdx.x;
  const int tid = threadIdx.x;
  __shared__ double red[256];
  double m = -1e300;
  for (int c = tid; c < KP; c += 256) m = fmax(m, (double)z[(size_t)r * KP + c]);
  red[tid] = m;
  __syncthreads();
  for (int off = 128; off; off >>= 1) {
    if (tid < off) red[tid] = fmax(red[tid], red[tid + off]);
    __syncthreads();
  }
  m = red[0];
  __syncthreads();
  double s = 0.0;
  for (int c = tid; c < KP; c += 256) s += exp((double)z[(size_t)r * KP + c] - m);
  red[tid] = s;
  __syncthreads();
  for (int off = 128; off; off >>= 1) {
    if (tid < off) red[tid] += red[tid + off];
    __syncthreads();
  }
  if (tid == 0) { rmax[r] = m; rsum[r] = red[0]; }
}

// ---------------- legacy masked scores transpose (fallback) -----------------
template <typename ZT>
__global__ __launch_bounds__(256) void k_scores(const ZT* __restrict__ z,
                                                const double* __restrict__ rmax,
                                                const double* __restrict__ rsum,
                                                float* __restrict__ scoresT) {
  __shared__ float st[64][65];
  const int c0 = blockIdx.x * 64, r0 = blockIdx.y * 64;
  const int tid = threadIdx.x;
  const int cc = tid & 63, rq = tid >> 6;
  for (int it = 0; it < 16; ++it) {
    int r = r0 + it * 4 + rq;
    int c = c0 + cc;
    if (c < KCLS) {
      double zz = (double)z[(size_t)r * KP + c];
      double sc = exp(zz - rmax[r]) / rsum[r];
      float f = (float)sc;
      st[cc][it * 4 + rq] = (f > 1e-4f) ? f : NEGV;
    }
  }
  __syncthreads();
  const int rr = tid & 63, cq = tid >> 6;
  for (int it = 0; it < 16; ++it) {
    int c = c0 + it * 4 + cq;
    if (c < KCLS) scoresT[(size_t)c * RR + r0 + rr] = st[it * 4 + cq][rr];
  }
}

// ---------------- box deltas (GEMV) + apply + clip -----------------
__global__ __launch_bounds__(256) void k_boxes(const float* __restrict__ feat,
                                               const float* __restrict__ wbox,
                                               const float* __restrict__ bbox,
                                               const float* __restrict__ props,
                                               float* __restrict__ boxes) {
  const int wid = threadIdx.x >> 6, lane = threadIdx.x & 63;
  const int r = blockIdx.x * 4 + wid;
  float p0 = 0, p1 = 0, p2 = 0, p3 = 0;
  for (int k = lane; k < DD; k += 64) {
    float f = feat[(size_t)r * DD + k];
    float4 w = *(const float4*)&wbox[k * 4];
    p0 = fmaf(f, w.x, p0);
    p1 = fmaf(f, w.y, p1);
    p2 = fmaf(f, w.z, p2);
    p3 = fmaf(f, w.w, p3);
  }
  for (int off = 32; off; off >>= 1) {
    p0 += __shfl_down(p0, off);
    p1 += __shfl_down(p1, off);
    p2 += __shfl_down(p2, off);
    p3 += __shfl_down(p3, off);
  }
  if (lane == 0) {
    p0 += bbox[0]; p1 += bbox[1]; p2 += bbox[2]; p3 += bbox[3];
    float4 pr = *(const float4*)&props[r * 4];
    float w = pr.z - pr.x, h = pr.w - pr.y;
    float cx = pr.x + 0.5f * w, cy = pr.y + 0.5f * h;
    float dx = p0 / 10.f, dy = p1 / 10.f;
    float dw = fminf(p2 / 5.f, SCLAMP), dh = fminf(p3 / 5.f, SCLAMP);
    float pcx = dx * w + cx, pcy = dy * h + cy;
    float pw = expf(dw) * w, ph = expf(dh) * h;
    float x1 = pcx - 0.5f * pw, y1 = pcy - 0.5f * ph;
    float x2 = pcx + 0.5f * pw, y2 = pcy + 0.5f * ph;
    x1 = fminf(fmaxf(x1, 0.f), 1333.f);
    x2 = fminf(fmaxf(x2, 0.f), 1333.f);
    y1 = fminf(fmaxf(y1, 0.f), 800.f);
    y2 = fminf(fmaxf(y2, 0.f), 800.f);
    *(float4*)&boxes[r * 4] = make_float4(x1, y1, x2, y2);
  }
}

// ---------------- per-class exact top-128 + NMS (register radix + shfl scan + wave NMS) ----
// Keys/selection bit-identical to lax.top_k order: key = (fmono(v)<<13) | (8191 - row).
template <bool DIRECT>
__global__ __launch_bounds__(256) void k_class(const float* __restrict__ scoresT,
                                               const float* __restrict__ lgf,
                                               const double* __restrict__ rmax,
                                               const double* __restrict__ rsum,
                                               const float* __restrict__ boxes,
                                               float* __restrict__ per_scores,
                                               int* __restrict__ per_idx,
                                               unsigned* __restrict__ hist1) {
  const int c = blockIdx.x, tid = threadIdx.x;
  const int lane = tid & 63, wid = tid >> 6;
  __shared__ unsigned hist[256];
  __shared__ unsigned wtot[4];
  __shared__ uint64_t skey[MM];
  __shared__ uint64_t s_prefix;
  __shared__ int s_need, s_cnt;

  // 32 values per thread, register-resident (fully unrolled indexing)
  unsigned u[32];
#pragma unroll
  for (int i = 0; i < 32; ++i) {
    const int r2 = tid + (i << 8);
    float s;
    if (DIRECT) {
      double sc = exp((double)lgf[(size_t)r2 * KP + c] - rmax[r2]) / rsum[r2];
      float f = (float)sc;
      s = (f > 1e-4f) ? f : NEGV;
    } else {
      s = scoresT[(size_t)c * RR + r2];
    }
    u[i] = fmono(s);
  }
  if (tid == 0) { s_prefix = 0; s_need = MM; s_cnt = 0; }
  __syncthreads();

  // 6-pass radix select (descending) on the 45-bit key; 4 barriers/pass
  for (int pass = 0; pass < 6; ++pass) {
    const int shift = 40 - 8 * pass;
    hist[tid] = 0;
    __syncthreads();
    const uint64_t pre = s_prefix;
    const int nd = s_need;
#pragma unroll
    for (int i = 0; i < 32; ++i) {
      uint64_t key = ((uint64_t)u[i] << 13) | (uint64_t)(8191 - (tid + (i << 8)));
      if ((key >> (shift + 8)) == (pre >> (shift + 8)))
        atomicAdd(&hist[(unsigned)(key >> shift) & 255u], 1u);
    }
    __syncthreads();
    const unsigned h = hist[tid];
    unsigned x = h;
    // intra-wave suffix-inclusive scan over this wave's 64 bins
#pragma unroll
    for (int off = 1; off < 64; off <<= 1) {
      unsigned y = __shfl_down(x, off);
      x += (lane + off < 64) ? y : 0u;
    }
    if (lane == 0) wtot[wid] = x;
    __syncthreads();
    for (int w2 = wid + 1; w2 < 4; ++w2) x += wtot[w2];  // cross-wave suffix
    const unsigned nxt = x - h;  // suffix at bin tid+1
    if ((int)x >= nd && (int)nxt < nd) {
      s_prefix = pre | ((uint64_t)tid << shift);
      s_need = nd - (int)nxt;
    }
    __syncthreads();
  }

  // collect the exactly-128 keys >= threshold (keys are unique)
  const uint64_t kthr = s_prefix;
#pragma unroll
  for (int i = 0; i < 32; ++i) {
    uint64_t key = ((uint64_t)u[i] << 13) | (uint64_t)(8191 - (tid + (i << 8)));
    if (key >= kthr) {
      int p = atomicAdd(&s_cnt, 1);
      if (p < MM) skey[p] = key;
    }
  }
  __syncthreads();

  // bitonic sort 128 keys descending (28 barrier stages)
  for (int kk2 = 2; kk2 <= MM; kk2 <<= 1)
    for (int j = kk2 >> 1; j > 0; j >>= 1) {
      __syncthreads();
      if (tid < MM) {
        int ixj = tid ^ j;
        if (ixj > tid) {
          uint64_t a = skey[tid], b = skey[ixj];
          bool desc = ((tid & kk2) == 0);
          if (desc ? (a < b) : (a > b)) { skey[tid] = b; skey[ixj] = a; }
        }
      }
    }
  __syncthreads();

  // wave-synchronous NMS: wave 0 holds 128 sorted boxes, 2 per lane; zero barriers
  if (wid == 0) {
    const uint64_t kA = skey[lane], kB = skey[lane + 64];
    const int iA = 8191 - (int)(kA & 0x1FFFu);
    const int iB = 8191 - (int)(kB & 0x1FFFu);
    const float vA = monof((unsigned)(kA >> 13));
    const float vB = monof((unsigned)(kB >> 13));
    const bool validA = vA > -5e8f, validB = vB > -5e8f;
    const float4 bA = *(const float4*)&boxes[iA * 4];
    const float4 bB = *(const float4*)&boxes[iB * 4];
    bool keepA = false, keepB = false;
    for (int i = 0; i < MM; ++i) {
      const int src = i & 63;
      const bool hi = (i >= 64);  // uniform per iteration
      float cx = hi ? bB.x : bA.x, cy = hi ? bB.y : bA.y;
      float cz = hi ? bB.z : bA.z, cw = hi ? bB.w : bA.w;
      float4 bi;
      bi.x = __shfl(cx, src);
      bi.y = __shfl(cy, src);
      bi.z = __shfl(cz, src);
      bi.w = __shfl(cw, src);
      const bool sA = keepA && (iou_f(bA, bi) > 0.5f);
      const bool sB = keepB && (iou_f(bB, bi) > 0.5f);
      const unsigned long long m = __ballot(sA) | __ballot(sB);
      const bool supp = (m != 0ull);
      if (!hi && lane == i) keepA = validA && !supp;
      if (hi && lane == (i - 64)) keepB = validB && !supp;
    }
    per_scores[(size_t)c * MM + lane] = keepA ? vA : NEGV;
    per_idx[(size_t)c * MM + lane] = iA;
    per_scores[(size_t)c * MM + lane + 64] = keepB ? vB : NEGV;
    per_idx[(size_t)c * MM + lane + 64] = iB;
    if (keepA) atomicAdd(&hist1[fmono(vA) >> 16], 1u);
    if (keepB) atomicAdd(&hist1[fmono(vB) >> 16], 1u);
  }
}

// ---------------- global top-300: two-level radix threshold + compact + small sort ----------
__global__ __launch_bounds__(1024) void k_sel1(const unsigned* __restrict__ hist, int* __restrict__ sel) {
  __shared__ unsigned red[1024];
  const int t = threadIdx.x;
  unsigned s = 0;
#pragma unroll 8
  for (int i = 0; i < 64; i++) s += hist[t * 64 + i];
  red[t] = s;
  __syncthreads();
  for (int off = 1; off < 1024; off <<= 1) {
    unsigned add = (t + off < 1024) ? red[t + off] : 0u;
    __syncthreads();
    red[t] += add;
    __syncthreads();
  }
  unsigned above = (t < 1023) ? red[t + 1] : 0u;
  if (red[t] >= (unsigned)TOPKN && above < (unsigned)TOPKN) {
    unsigned run = above;
    for (int b = 63; b >= 0; --b) {
      unsigned cb = hist[t * 64 + b];
      if (run < (unsigned)TOPKN && run + cb >= (unsigned)TOPKN) {
        sel[0] = t * 64 + b;
        sel[1] = (int)((unsigned)TOPKN - run);
      }
      run += cb;
    }
  }
}

__global__ __launch_bounds__(256) void k_hist2(const float* __restrict__ per_scores,
                                               const int* __restrict__ sel,
                                               unsigned* __restrict__ hist2) {
  const int f = blockIdx.x * 256 + threadIdx.x;
  if (f >= NFLAT) return;
  const unsigned p16 = (unsigned)sel[0];
  unsigned u = fmono(per_scores[f]);
  if ((u >> 16) == p16) atomicAdd(&hist2[u & 0xFFFFu], 1u);
}

__global__ __launch_bounds__(1024) void k_sel2(const unsigned* __restrict__ hist, int* __restrict__ sel) {
  __shared__ unsigned red[1024];
  __shared__ unsigned sneed, sp16;
  const int t = threadIdx.x;
  if (t == 0) { sneed = (unsigned)sel[1]; sp16 = (unsigned)sel[0]; }
  __syncthreads();
  const unsigned NEED = sneed;
  unsigned s = 0;
#pragma unroll 8
  for (int i = 0; i < 64; i++) s += hist[t * 64 + i];
  red[t] = s;
  __syncthreads();
  for (int off = 1; off < 1024; off <<= 1) {
    unsigned add = (t + off < 1024) ? red[t + off] : 0u;
    __syncthreads();
    red[t] += add;
    __syncthreads();
  }
  unsigned above = (t < 1023) ? red[t + 1] : 0u;
  if (red[t] >= NEED && above < NEED) {
    unsigned run = above;
    for (int b = 63; b >= 0; --b) {
      unsigned cb = hist[t * 64 + b];
      if (run < NEED && run + cb >= NEED) {
        sel[2] = (int)((sp16 << 16) | (unsigned)(t * 64 + b));
      }
      run += cb;
    }
  }
}

__global__ __launch_bounds__(256) void k_compact(const float* __restrict__ per_scores,
                                                 int* __restrict__ sel,
                                                 uint64_t* __restrict__ deflist,
                                                 uint64_t* __restrict__ tielist) {
  const int f = blockIdx.x * 256 + threadIdx.x;
  if (f >= NFLAT) return;
  const unsigned v32 = (unsigned)sel[2];
  unsigned u = fmono(per_scores[f]);
  if (u < v32) return;
  uint64_t key = ((uint64_t)u << 18) | (uint64_t)(262143 - f);
  if (u > v32) {
    int p = atomicAdd(&sel[4], 1);
    if (p < 512) deflist[p] = key;
  } else {
    int p = atomicAdd(&sel[5], 1);
    if (p < 512) tielist[p] = key;
  }
}

__global__ __launch_bounds__(1024) void k_final(const uint64_t* __restrict__ deflist,
                                                const uint64_t* __restrict__ tielist,
                                                const int* __restrict__ sel,
                                                const int* __restrict__ per_idx,
                                                const float* __restrict__ boxes,
                                                float* __restrict__ out) {
  __shared__ uint64_t skey[1024];
  const int t = threadIdx.x;
  const int n0 = min(sel[4], 512);
  const int n1 = min(sel[5], 512);
  uint64_t k = 0;
  if (t < n0) k = deflist[t];
  else if (t - n0 < n1) k = tielist[t - n0];
  skey[t] = k;
  __syncthreads();
  for (int kk2 = 2; kk2 <= 1024; kk2 <<= 1)
    for (int j = kk2 >> 1; j > 0; j >>= 1) {
      __syncthreads();
      int ixj = t ^ j;
      if (ixj > t) {
        uint64_t a = skey[t], b = skey[ixj];
        bool desc = ((t & kk2) == 0);
        if (desc ? (a < b) : (a > b)) { skey[t] = b; skey[ixj] = a; }
      }
    }
  __syncthreads();
  if (t < TOPKN) {
    uint64_t key = skey[t];
    int f = 262143 - (int)(key & 0x3FFFFu);
    float val = monof((unsigned)(key >> 18));
    int cls = f >> 7;
    int prop = per_idx[f];
    float4 b = *(const float4*)&boxes[prop * 4];
    float* o = &out[t * 6];
    o[0] = b.x; o[1] = b.y; o[2] = b.z; o[3] = b.w;
    o[4] = val; o[5] = (float)cls;
  }
}

extern "C" void kernel_launch(void* const* d_in, const int* in_sizes, int n_in,
                              void* d_out, int out_size, void* d_ws, size_t ws_size,
                              hipStream_t stream) {
  const float* feat = (const float*)d_in[0];
  const float* props = (const float*)d_in[1];
  const float* wcls = (const float*)d_in[2];
  const float* bcls = (const float*)d_in[3];
  const float* wbox = (const float*)d_in[4];
  const float* bbox = (const float*)d_in[5];
  float* out = (float*)d_out;
  char* ws = (char*)d_ws;

  size_t o = 0;
  auto al = [&](size_t b) { size_t cur = o; o += (b + 255) & ~(size_t)255; return cur; };
  const size_t o_boxes = al((size_t)RR * 4 * 4);
  const size_t o_ps = al((size_t)KCLS * MM * 4);
  const size_t o_pi = al((size_t)KCLS * MM * 4);
  const size_t o_rmax = al((size_t)RR * 8);
  const size_t o_rsum = al((size_t)RR * 8);
  const size_t o_hist1 = al((size_t)65536 * 4);
  const size_t o_hist2 = al((size_t)65536 * 4);
  const size_t o_sel = al((size_t)256);
  const size_t o_def = al((size_t)512 * 8);
  const size_t o_tie = al((size_t)512 * 8);
  const size_t fixed_end = o;

  float* boxes = (float*)(ws + o_boxes);
  float* per_scores = (float*)(ws + o_ps);
  int* per_idx = (int*)(ws + o_pi);
  double* rmax = (double*)(ws + o_rmax);
  double* rsum = (double*)(ws + o_rsum);
  unsigned* hist1 = (unsigned*)(ws + o_hist1);
  unsigned* hist2 = (unsigned*)(ws + o_hist2);
  int* sel = (int*)(ws + o_sel);
  uint64_t* deflist = (uint64_t*)(ws + o_def);
  uint64_t* tielist = (uint64_t*)(ws + o_tie);

  // MFMA-path layout (with aliasing): A-planes (also scoresA), Bt-planes, logits (also scoresT)
  const size_t sz_A3 = ((size_t)3 * RR * DD * 2 + 255) & ~(size_t)255;      // 50.3 MB
  const size_t sz_Bt = ((size_t)3 * NB * DD * 2 + 255) & ~(size_t)255;      // 7.9 MB
  const size_t sz_lg2 = ((size_t)RR * KP2 * 8 + 255) & ~(size_t)255;        // 79.7 MB
  const size_t needM = fixed_end + sz_A3 + sz_Bt + sz_lg2;

  const size_t sz_scT = ((size_t)KCLS * RR * 4 + 255) & ~(size_t)255;
  const size_t sz_lgD = ((size_t)RR * KP * 8 + 255) & ~(size_t)255;
  const size_t sz_lgF = ((size_t)RR * KP * 4 + 255) & ~(size_t)255;

  const bool pathM = ws_size >= needM;
  const bool pathA = !pathM && ws_size >= fixed_end + sz_scT + sz_lgD;
  const bool pathB = !pathM && !pathA && ws_size >= fixed_end + sz_scT + sz_lgF;

  const int gFlat = (NFLAT + 255) / 256;

  hipMemsetAsync(ws + o_hist1, 0, (o_sel - o_hist1) + 256, stream);

  k_boxes<<<RR / 4, 256, 0, stream>>>(feat, wbox, bbox, props, boxes);

  if (pathM) {
    unsigned short* Ap = (unsigned short*)(ws + fixed_end);
    unsigned short* Btp = (unsigned short*)(ws + fixed_end + sz_A3);
    double* lg = (double*)(ws + fixed_end + sz_A3 + sz_Bt);
    float* scoresA = (float*)(ws + fixed_end);                 // aliases Ap (dead after GEMM)
    float* scoresT = (float*)(ws + fixed_end + sz_A3 + sz_Bt); // aliases lg (dead after softmax)

    k_split_feat<<<(RR * DD / 4) / 256, 256, 0, stream>>>(feat, Ap);
    k_split_w<<<dim3(NB / 64, DD / 64), 256, 0, stream>>>(wcls, Btp);
    k_gemm_mfma<<<dim3(NB / 128, RR / 128), 512, 0, stream>>>(Ap, Btp, bcls, lg);
    k_softmax<<<RR, 256, 0, stream>>>(lg, scoresA);
    k_transposeS<<<dim3(KP2 / 64, RR / 64), 256, 0, stream>>>(scoresA, scoresT);
    k_class<false><<<KCLS, 256, 0, stream>>>(scoresT, nullptr, rmax, rsum, boxes, per_scores, per_idx, hist1);
  } else if (pathA) {
    float* scoresT = (float*)(ws + fixed_end);
    double* lg = (double*)(ws + fixed_end + sz_scT);
    k_gemm<double><<<dim3(19, 128), 256, 0, stream>>>(feat, wcls, bcls, lg);
    k_rowstats<double><<<RR, 256, 0, stream>>>(lg, rmax, rsum);
    k_scores<double><<<dim3(19, 128), 256, 0, stream>>>(lg, rmax, rsum, scoresT);
    k_class<false><<<KCLS, 256, 0, stream>>>(scoresT, nullptr, rmax, rsum, boxes, per_scores, per_idx, hist1);
  } else if (pathB) {
    float* scoresT = (float*)(ws + fixed_end);
    float* lg = (float*)(ws + fixed_end + sz_scT);
    k_gemm<float><<<dim3(19, 128), 256, 0, stream>>>(feat, wcls, bcls, lg);
    k_rowstats<float><<<RR, 256, 0, stream>>>(lg, rmax, rsum);
    k_scores<float><<<dim3(19, 128), 256, 0, stream>>>(lg, rmax, rsum, scoresT);
    k_class<false><<<KCLS, 256, 0, stream>>>(scoresT, nullptr, rmax, rsum, boxes, per_scores, per_idx, hist1);
  } else {
    float* lg = (float*)(ws + fixed_end);
    k_gemm<float><<<dim3(19, 128), 256, 0, stream>>>(feat, wcls, bcls, lg);
    k_rowstats<float><<<RR, 256, 0, stream>>>(lg, rmax, rsum);
    k_class<true><<<KCLS, 256, 0, stream>>>(nullptr, lg, rmax, rsum, boxes, per_scores, per_idx, hist1);
  }

  k_sel1<<<1, 1024, 0, stream>>>(hist1, sel);
  k_hist2<<<gFlat, 256, 0, stream>>>(per_scores, sel, hist2);
  k_sel2<<<1, 1024, 0, stream>>>(hist2, sel);
  k_compact<<<gFlat, 256, 0, stream>>>(per_scores, sel, deflist, tielist);
  k_final<<<1, 1024, 0, stream>>>(deflist, tielist, sel, per_idx, boxes, out);
}

// Round 14
// 617.419 us; speedup vs baseline: 1.6329x; 1.0259x over previous
//
#include <hip/hip_runtime.h>
#include <math.h>
#include <stdint.h>

#define RR 8192
#define DD 1024
#define KCLS 1203
#define KP 1204
#define KP2 1216   // padded logits/scores stride (MFMA path)
#define NB 1280    // padded B columns (10 tiles of 128)
#define MM 128
#define TOPKN 300
#define NFLAT (KCLS * MM)
#define NEGV (-1e9f)
#define SCLAMP 4.1351665567423563f

typedef __attribute__((ext_vector_type(8))) short bf16x8;
typedef __attribute__((ext_vector_type(4))) float f32x4;

__device__ __forceinline__ unsigned fmono(float f) {
  unsigned u = __float_as_uint(f);
  return (u & 0x80000000u) ? ~u : (u | 0x80000000u);
}
__device__ __forceinline__ float monof(unsigned u) {
  return __uint_as_float((u & 0x80000000u) ? (u ^ 0x80000000u) : ~u);
}
__device__ __forceinline__ float iou_f(float4 a, float4 b) {
  float areaA = (a.z - a.x) * (a.w - a.y);
  float areaB = (b.z - b.x) * (b.w - b.y);
  float lx = fmaxf(a.x, b.x), ly = fmaxf(a.y, b.y);
  float rx = fminf(a.z, b.z), ry = fminf(a.w, b.w);
  float w = fmaxf(rx - lx, 0.f), h = fmaxf(ry - ly, 0.f);
  float inter = w * h;
  return inter / (areaA + areaB - inter + 1e-6f);
}

__device__ __forceinline__ unsigned short bf16_rn(float x) {
  unsigned u = __float_as_uint(x);
  unsigned r = (u + 0x7FFFu + ((u >> 16) & 1u)) >> 16;
  return (unsigned short)r;
}
__device__ __forceinline__ float bf16f(unsigned short h) {
  return __uint_as_float(((unsigned)h) << 16);
}
// exact 3-way split: x = hi + mid + lo + eps, |eps| ~ 2^-25|x|
__device__ __forceinline__ void split3(float x, unsigned short& h, unsigned short& m2, unsigned short& l) {
  h = bf16_rn(x);
  float r1 = x - bf16f(h);
  m2 = bf16_rn(r1);
  float r2 = r1 - bf16f(m2);
  l = bf16_rn(r2);
}

// wave-aggregated LDS histogram add: collapses same-bin updates (score floats cluster
// -> pass-0 radix bins are degenerate; plain atomics serialized 8192-way, m-round7 PMC)
__device__ __forceinline__ void hist_add_wave(unsigned* h, unsigned bin, bool act, int lane) {
  unsigned long long ball = __ballot(act);
  if (ball == 0ull) return;                      // wave-uniform
  int first = __ffsll(ball) - 1;
  unsigned b0 = __shfl(bin, first);
  if (__all(!act || (bin == b0))) {
    if (lane == first) atomicAdd(&h[b0], (unsigned)__popcll(ball));
  } else if (act) {
    atomicAdd(&h[bin], 1u);
  }
}

// ---------------- split feat -> 3 bf16 planes [3][RR][DD] -----------------
__global__ __launch_bounds__(256) void k_split_feat(const float* __restrict__ feat,
                                                    unsigned short* __restrict__ Ap) {
  const size_t i4 = (size_t)blockIdx.x * 256 + threadIdx.x;  // float4 index
  float4 v = *(const float4*)&feat[i4 * 4];
  ushort4 h, m2, l;
  split3(v.x, h.x, m2.x, l.x);
  split3(v.y, h.y, m2.y, l.y);
  split3(v.z, h.z, m2.z, l.z);
  split3(v.w, h.w, m2.w, l.w);
  const size_t P = (size_t)RR * DD;
  *(ushort4*)&Ap[0 * P + i4 * 4] = h;
  *(ushort4*)&Ap[1 * P + i4 * 4] = m2;
  *(ushort4*)&Ap[2 * P + i4 * 4] = l;
}

// ---------------- split+transpose w_cls -> 3 bf16 planes Bt [3][NB][DD] -----------------
__global__ __launch_bounds__(256) void k_split_w(const float* __restrict__ wcls,
                                                 unsigned short* __restrict__ Btp) {
  __shared__ float st[64][65];
  const int c0 = blockIdx.x * 64, k0 = blockIdx.y * 64;
  const int tid = threadIdx.x;
  const int cc = tid & 63, kq = tid >> 6;
  for (int it = 0; it < 16; ++it) {
    int kl = it * 4 + kq;
    int c = c0 + cc;
    st[cc][kl] = (c < KP) ? wcls[(size_t)(k0 + kl) * KP + c] : 0.f;
  }
  __syncthreads();
  const int kk = tid & 63, cq = tid >> 6;
  const size_t P = (size_t)NB * DD;
  for (int it = 0; it < 16; ++it) {
    int cl = it * 4 + cq;
    float v = st[cl][kk];
    unsigned short h, m2, l;
    split3(v, h, m2, l);
    size_t off = (size_t)(c0 + cl) * DD + k0 + kk;
    Btp[0 * P + off] = h;
    Btp[1 * P + off] = m2;
    Btp[2 * P + off] = l;
  }
}

// ---------------- MFMA GEMM: logits = feat @ w_cls + b_cls (double out) -----------------
// 128x128 tile, BK=32, 8 waves (2Mx4N), wave=64x32, 16x16x32 bf16 MFMA, 6-term split.
// fp64 fold every 64 K -> logit error ~1.3e-7.
__global__ __launch_bounds__(512) void k_gemm_mfma(const unsigned short* __restrict__ Ap,
                                                   const unsigned short* __restrict__ Btp,
                                                   const float* __restrict__ bcls,
                                                   double* __restrict__ outlg) {
  __shared__ unsigned short As[3][128][40];  // padded: 80B rows -> 2-way bank conflict only
  __shared__ unsigned short Bs[3][128][40];
  const int tid = threadIdx.x;
  const int r0 = blockIdx.y * 128;
  const int c0 = blockIdx.x * 128;
  const int wid = tid >> 6, lane = tid & 63;
  const int wm = wid >> 2, wn = wid & 3;
  const int wrow = wm * 64, wcol = wn * 32;
  const int l15 = lane & 15, l4 = lane >> 4;

  f32x4 acc[4][2];
  double acc64[4][2][4];
#pragma unroll
  for (int mf = 0; mf < 4; ++mf)
#pragma unroll
    for (int nf = 0; nf < 2; ++nf) {
      acc[mf][nf] = (f32x4){0.f, 0.f, 0.f, 0.f};
#pragma unroll
      for (int q = 0; q < 4; ++q) acc64[mf][nf][q] = 0.0;
    }

  const size_t PA = (size_t)RR * DD;
  const size_t PB = (size_t)NB * DD;

  for (int kt = 0; kt < 32; ++kt) {
    __syncthreads();
#pragma unroll
    for (int it = 0; it < 3; ++it) {
      int c2 = it * 512 + tid;         // 0..1535 : 3 planes x 128 rows x 4 chunks
      int plane = c2 >> 9;
      int rr2 = (c2 >> 2) & 127;
      int jc = (c2 & 3) << 3;          // element offset 0,8,16,24
      const uint4 av = *(const uint4*)(Ap + (size_t)plane * PA + ((size_t)(r0 + rr2)) * DD + kt * 32 + jc);
      const uint4 bv = *(const uint4*)(Btp + (size_t)plane * PB + ((size_t)(c0 + rr2)) * DD + kt * 32 + jc);
      *(uint4*)&As[plane][rr2][jc] = av;
      *(uint4*)&Bs[plane][rr2][jc] = bv;
    }
    __syncthreads();

    bf16x8 bf[2][3];
#pragma unroll
    for (int nf = 0; nf < 2; ++nf)
#pragma unroll
      for (int p = 0; p < 3; ++p)
        bf[nf][p] = *(const bf16x8*)&Bs[p][wcol + nf * 16 + l15][l4 * 8];

#pragma unroll
    for (int mf = 0; mf < 4; ++mf) {
      bf16x8 a0 = *(const bf16x8*)&As[0][wrow + mf * 16 + l15][l4 * 8];
      bf16x8 a1 = *(const bf16x8*)&As[1][wrow + mf * 16 + l15][l4 * 8];
      bf16x8 a2 = *(const bf16x8*)&As[2][wrow + mf * 16 + l15][l4 * 8];
#pragma unroll
      for (int nf = 0; nf < 2; ++nf) {
        f32x4 a = acc[mf][nf];
        a = __builtin_amdgcn_mfma_f32_16x16x32_bf16(a0, bf[nf][0], a, 0, 0, 0);  // hh
        a = __builtin_amdgcn_mfma_f32_16x16x32_bf16(a0, bf[nf][1], a, 0, 0, 0);  // hm
        a = __builtin_amdgcn_mfma_f32_16x16x32_bf16(a1, bf[nf][0], a, 0, 0, 0);  // mh
        a = __builtin_amdgcn_mfma_f32_16x16x32_bf16(a0, bf[nf][2], a, 0, 0, 0);  // hl
        a = __builtin_amdgcn_mfma_f32_16x16x32_bf16(a2, bf[nf][0], a, 0, 0, 0);  // lh
        a = __builtin_amdgcn_mfma_f32_16x16x32_bf16(a1, bf[nf][1], a, 0, 0, 0);  // mm
        acc[mf][nf] = a;
      }
    }

    if (kt & 1) {  // fold into fp64 every 64 K
#pragma unroll
      for (int mf = 0; mf < 4; ++mf)
#pragma unroll
        for (int nf = 0; nf < 2; ++nf) {
#pragma unroll
          for (int q = 0; q < 4; ++q) acc64[mf][nf][q] += (double)acc[mf][nf][q];
          acc[mf][nf] = (f32x4){0.f, 0.f, 0.f, 0.f};
        }
    }
  }

#pragma unroll
  for (int mf = 0; mf < 4; ++mf)
#pragma unroll
    for (int nf = 0; nf < 2; ++nf) {
      int c = c0 + wcol + nf * 16 + l15;
      if (c < KP) {
#pragma unroll
        for (int q = 0; q < 4; ++q) {
          int r = r0 + wrow + mf * 16 + l4 * 4 + q;
          outlg[(size_t)r * KP2 + c] = acc64[mf][nf][q] + (double)bcls[c];
        }
      }
    }
}

// ---------------- fused per-row softmax (double) -> masked f32 scores [row][class] ---------
__global__ __launch_bounds__(256) void k_softmax(const double* __restrict__ lg,
                                                 float* __restrict__ scoresA) {
  const int r = blockIdx.x;
  const int tid = threadIdx.x;
  __shared__ double ex[KP];
  __shared__ double red[256];
  double m = -1e300;
  for (int c = tid; c < KP; c += 256) {
    double z = lg[(size_t)r * KP2 + c];
    ex[c] = z;
    m = fmax(m, z);
  }
  red[tid] = m;
  __syncthreads();
  for (int off = 128; off; off >>= 1) {
    if (tid < off) red[tid] = fmax(red[tid], red[tid + off]);
    __syncthreads();
  }
  m = red[0];
  __syncthreads();
  double s = 0.0;
  for (int c = tid; c < KP; c += 256) {
    double e = exp(ex[c] - m);
    ex[c] = e;
    s += e;
  }
  red[tid] = s;
  __syncthreads();
  for (int off = 128; off; off >>= 1) {
    if (tid < off) red[tid] += red[tid + off];
    __syncthreads();
  }
  s = red[0];
  __syncthreads();
  for (int c = tid; c < KCLS; c += 256) {
    float f = (float)(ex[c] / s);
    scoresA[(size_t)r * KP2 + c] = (f > 1e-4f) ? f : NEGV;
  }
}

// ---------------- f32 transpose: scoresA[row][class] -> scoresT[class][row] ---------------
__global__ __launch_bounds__(256) void k_transposeS(const float* __restrict__ scoresA,
                                                    float* __restrict__ scoresT) {
  __shared__ float st[64][65];
  const int c0 = blockIdx.x * 64, r0 = blockIdx.y * 64;
  const int tid = threadIdx.x;
  const int cc = tid & 63, rq = tid >> 6;
  for (int it = 0; it < 16; ++it) {
    int r = r0 + it * 4 + rq;
    int c = c0 + cc;
    if (c < KCLS) st[cc][it * 4 + rq] = scoresA[(size_t)r * KP2 + c];
  }
  __syncthreads();
  const int rr = tid & 63, cq = tid >> 6;
  for (int it = 0; it < 16; ++it) {
    int c = c0 + it * 4 + cq;
    if (c < KCLS) scoresT[(size_t)c * RR + r0 + rr] = st[it * 4 + cq][rr];
  }
}

// ---------------- legacy fp32-vector GEMM (fallback) -------------
template <typename ZT>
__global__ __launch_bounds__(256) void k_gemm(const float* __restrict__ feat,
                                              const float* __restrict__ wcls,
                                              const float* __restrict__ bcls,
                                              ZT* __restrict__ out) {
  __shared__ float As[16][64];
  __shared__ float Bs[16][64];
  const int tid = threadIdx.x;
  const int c0 = blockIdx.x * 64;
  const int r0 = blockIdx.y * 64;
  const int tx4 = (tid & 15) << 2;
  const int ty4 = (tid >> 4) << 2;
  const int arow = tid >> 2, akq = (tid & 3) << 2;
  const int bk = tid >> 4, bcol = (tid & 15) << 2;

  float fa[4][4];
  double da[4][4];
#pragma unroll
  for (int i = 0; i < 4; i++)
#pragma unroll
    for (int j = 0; j < 4; j++) { fa[i][j] = 0.f; da[i][j] = 0.0; }

  for (int kt = 0; kt < DD / 16; ++kt) {
    float4 av = *(const float4*)&feat[(size_t)(r0 + arow) * DD + kt * 16 + akq];
    float4 bv;
    {
      int gc = c0 + bcol;
      const float* wrow = &wcls[(size_t)(kt * 16 + bk) * KP];
      if (gc + 3 < KP) {
        bv = *(const float4*)&wrow[gc];
      } else {
        bv.x = (gc + 0 < KP) ? wrow[gc + 0] : 0.f;
        bv.y = (gc + 1 < KP) ? wrow[gc + 1] : 0.f;
        bv.z = (gc + 2 < KP) ? wrow[gc + 2] : 0.f;
        bv.w = (gc + 3 < KP) ? wrow[gc + 3] : 0.f;
      }
    }
    __syncthreads();
    As[akq + 0][arow] = av.x;
    As[akq + 1][arow] = av.y;
    As[akq + 2][arow] = av.z;
    As[akq + 3][arow] = av.w;
    *(float4*)&Bs[bk][bcol] = bv;
    __syncthreads();
#pragma unroll
    for (int k = 0; k < 16; ++k) {
      float4 a = *(const float4*)&As[k][ty4];
      float4 b = *(const float4*)&Bs[k][tx4];
      float ax[4] = {a.x, a.y, a.z, a.w};
      float bx[4] = {b.x, b.y, b.z, b.w};
#pragma unroll
      for (int i = 0; i < 4; i++)
#pragma unroll
        for (int j = 0; j < 4; j++) fa[i][j] = fmaf(ax[i], bx[j], fa[i][j]);
    }
#pragma unroll
    for (int i = 0; i < 4; i++)
#pragma unroll
      for (int j = 0; j < 4; j++) { da[i][j] += (double)fa[i][j]; fa[i][j] = 0.f; }
  }
#pragma unroll
  for (int i = 0; i < 4; i++) {
    int r = r0 + ty4 + i;
#pragma unroll
    for (int j = 0; j < 4; j++) {
      int c = c0 + tx4 + j;
      if (c < KP) out[(size_t)r * KP + c] = (ZT)(da[i][j] + (double)bcls[c]);
    }
  }
}

// ---------------- legacy rowstats (fallback) -----------------
template <typename ZT>
__global__ __launch_bounds__(256) void k_rowstats(const ZT* __restrict__ z,
                                                  double* __restrict__ rmax,
                                                  double* __restrict__ rsum) {
  const int r = blockIdx.x;
  const int tid = threadIdx.x;
  __shared__ double red[256];
  double m = -1e300;
  for (int c = tid; c < KP; c += 256) m = fmax(m, (double)z[(size_t)r * KP + c]);
  red[tid] = m;
  __syncthreads();
  for (int off = 128; off; off >>= 1) {
    if (tid < off) red[tid] = fmax(red[tid], red[tid + off]);
    __syncthreads();
  }
  m = red[0];
  __syncthreads();
  double s = 0.0;
  for (int c = tid; c < KP; c += 256) s += exp((double)z[(size_t)r * KP + c] - m);
  red[tid] = s;
  __syncthreads();
  for (int off = 128; off; off >>= 1) {
    if (tid < off) red[tid] += red[tid + off];
    __syncthreads();
  }
  if (tid == 0) { rmax[r] = m; rsum[r] = red[0]; }
}

// ---------------- legacy masked scores transpose (fallback) -----------------
template <typename ZT>
__global__ __launch_bounds__(256) void k_scores(const ZT* __restrict__ z,
                                                const double* __restrict__ rmax,
                                                const double* __restrict__ rsum,
                                                float* __restrict__ scoresT) {
  __shared__ float st[64][65];
  const int c0 = blockIdx.x * 64, r0 = blockIdx.y * 64;
  const int tid = threadIdx.x;
  const int cc = tid & 63, rq = tid >> 6;
  for (int it = 0; it < 16; ++it) {
    int r = r0 + it * 4 + rq;
    int c = c0 + cc;
    if (c < KCLS) {
      double zz = (double)z[(size_t)r * KP + c];
      double sc = exp(zz - rmax[r]) / rsum[r];
      float f = (float)sc;
      st[cc][it * 4 + rq] = (f > 1e-4f) ? f : NEGV;
    }
  }
  __syncthreads();
  const int rr = tid & 63, cq = tid >> 6;
  for (int it = 0; it < 16; ++it) {
    int c = c0 + it * 4 + cq;
    if (c < KCLS) scoresT[(size_t)c * RR + r0 + rr] = st[it * 4 + cq][rr];
  }
}

// ---------------- box deltas (GEMV) + apply + clip -----------------
__global__ __launch_bounds__(256) void k_boxes(const float* __restrict__ feat,
                                               const float* __restrict__ wbox,
                                               const float* __restrict__ bbox,
                                               const float* __restrict__ props,
                                               float* __restrict__ boxes) {
  const int wid = threadIdx.x >> 6, lane = threadIdx.x & 63;
  const int r = blockIdx.x * 4 + wid;
  float p0 = 0, p1 = 0, p2 = 0, p3 = 0;
  for (int k = lane; k < DD; k += 64) {
    float f = feat[(size_t)r * DD + k];
    float4 w = *(const float4*)&wbox[k * 4];
    p0 = fmaf(f, w.x, p0);
    p1 = fmaf(f, w.y, p1);
    p2 = fmaf(f, w.z, p2);
    p3 = fmaf(f, w.w, p3);
  }
  for (int off = 32; off; off >>= 1) {
    p0 += __shfl_down(p0, off);
    p1 += __shfl_down(p1, off);
    p2 += __shfl_down(p2, off);
    p3 += __shfl_down(p3, off);
  }
  if (lane == 0) {
    p0 += bbox[0]; p1 += bbox[1]; p2 += bbox[2]; p3 += bbox[3];
    float4 pr = *(const float4*)&props[r * 4];
    float w = pr.z - pr.x, h = pr.w - pr.y;
    float cx = pr.x + 0.5f * w, cy = pr.y + 0.5f * h;
    float dx = p0 / 10.f, dy = p1 / 10.f;
    float dw = fminf(p2 / 5.f, SCLAMP), dh = fminf(p3 / 5.f, SCLAMP);
    float pcx = dx * w + cx, pcy = dy * h + cy;
    float pw = expf(dw) * w, ph = expf(dh) * h;
    float x1 = pcx - 0.5f * pw, y1 = pcy - 0.5f * ph;
    float x2 = pcx + 0.5f * pw, y2 = pcy + 0.5f * ph;
    x1 = fminf(fmaxf(x1, 0.f), 1333.f);
    x2 = fminf(fmaxf(x2, 0.f), 1333.f);
    y1 = fminf(fmaxf(y1, 0.f), 800.f);
    y2 = fminf(fmaxf(y2, 0.f), 800.f);
    *(float4*)&boxes[r * 4] = make_float4(x1, y1, x2, y2);
  }
}

// ---------------- per-class exact top-128 + NMS (register radix + shfl scan + wave NMS) ----
// Keys/selection bit-identical to lax.top_k order: key = (fmono(v)<<13) | (8191 - row).
template <bool DIRECT>
__global__ __launch_bounds__(256) void k_class(const float* __restrict__ scoresT,
                                               const float* __restrict__ lgf,
                                               const double* __restrict__ rmax,
                                               const double* __restrict__ rsum,
                                               const float* __restrict__ boxes,
                                               float* __restrict__ per_scores,
                                               int* __restrict__ per_idx,
                                               unsigned* __restrict__ hist1) {
  const int c = blockIdx.x, tid = threadIdx.x;
  const int lane = tid & 63, wid = tid >> 6;
  __shared__ unsigned hist4[4][256];   // per-wave copies: no inter-wave atomic contention
  __shared__ unsigned wtot[4];
  __shared__ uint64_t skey[MM];
  __shared__ uint64_t s_prefix;
  __shared__ int s_need, s_cnt;

  // 32 values per thread, register-resident (fully unrolled indexing)
  unsigned u[32];
#pragma unroll
  for (int i = 0; i < 32; ++i) {
    const int r2 = tid + (i << 8);
    float s;
    if (DIRECT) {
      double sc = exp((double)lgf[(size_t)r2 * KP + c] - rmax[r2]) / rsum[r2];
      float f = (float)sc;
      s = (f > 1e-4f) ? f : NEGV;
    } else {
      s = scoresT[(size_t)c * RR + r2];
    }
    u[i] = fmono(s);
  }
  if (tid == 0) { s_prefix = 0; s_need = MM; s_cnt = 0; }
  __syncthreads();

  // 6-pass radix select (descending) on the 45-bit key; wave-aggregated histogram
  for (int pass = 0; pass < 6; ++pass) {
    const int shift = 40 - 8 * pass;
#pragma unroll
    for (int w2 = 0; w2 < 4; ++w2) hist4[w2][tid] = 0;
    __syncthreads();
    const uint64_t pre = s_prefix;
    const int nd = s_need;
    unsigned* myh = hist4[wid];
#pragma unroll
    for (int i = 0; i < 32; ++i) {
      uint64_t key = ((uint64_t)u[i] << 13) | (uint64_t)(8191 - (tid + (i << 8)));
      const bool act = ((key >> (shift + 8)) == (pre >> (shift + 8)));
      const unsigned bin = (unsigned)(key >> shift) & 255u;
      hist_add_wave(myh, bin, act, lane);
    }
    __syncthreads();
    const unsigned h = hist4[0][tid] + hist4[1][tid] + hist4[2][tid] + hist4[3][tid];
    unsigned x = h;
    // intra-wave suffix-inclusive scan over this wave's 64 bins
#pragma unroll
    for (int off = 1; off < 64; off <<= 1) {
      unsigned y = __shfl_down(x, off);
      x += (lane + off < 64) ? y : 0u;
    }
    if (lane == 0) wtot[wid] = x;
    __syncthreads();
    for (int w2 = wid + 1; w2 < 4; ++w2) x += wtot[w2];  // cross-wave suffix
    const unsigned nxt = x - h;  // suffix at bin tid+1
    if ((int)x >= nd && (int)nxt < nd) {
      s_prefix = pre | ((uint64_t)tid << shift);
      s_need = nd - (int)nxt;
    }
    __syncthreads();
  }

  // collect the exactly-128 keys >= threshold (keys are unique)
  const uint64_t kthr = s_prefix;
#pragma unroll
  for (int i = 0; i < 32; ++i) {
    uint64_t key = ((uint64_t)u[i] << 13) | (uint64_t)(8191 - (tid + (i << 8)));
    if (key >= kthr) {
      int p = atomicAdd(&s_cnt, 1);
      if (p < MM) skey[p] = key;
    }
  }
  __syncthreads();

  // bitonic sort 128 keys descending (28 barrier stages)
  for (int kk2 = 2; kk2 <= MM; kk2 <<= 1)
    for (int j = kk2 >> 1; j > 0; j >>= 1) {
      __syncthreads();
      if (tid < MM) {
        int ixj = tid ^ j;
        if (ixj > tid) {
          uint64_t a = skey[tid], b = skey[ixj];
          bool desc = ((tid & kk2) == 0);
          if (desc ? (a < b) : (a > b)) { skey[tid] = b; skey[ixj] = a; }
        }
      }
    }
  __syncthreads();

  // wave-synchronous NMS: wave 0 holds 128 sorted boxes, 2 per lane; zero barriers
  if (wid == 0) {
    const uint64_t kA = skey[lane], kB = skey[lane + 64];
    const int iA = 8191 - (int)(kA & 0x1FFFu);
    const int iB = 8191 - (int)(kB & 0x1FFFu);
    const float vA = monof((unsigned)(kA >> 13));
    const float vB = monof((unsigned)(kB >> 13));
    const bool validA = vA > -5e8f, validB = vB > -5e8f;
    const float4 bA = *(const float4*)&boxes[iA * 4];
    const float4 bB = *(const float4*)&boxes[iB * 4];
    bool keepA = false, keepB = false;
    for (int i = 0; i < MM; ++i) {
      const int src = i & 63;
      const bool hi = (i >= 64);  // uniform per iteration
      float cx = hi ? bB.x : bA.x, cy = hi ? bB.y : bA.y;
      float cz = hi ? bB.z : bA.z, cw = hi ? bB.w : bA.w;
      float4 bi;
      bi.x = __shfl(cx, src);
      bi.y = __shfl(cy, src);
      bi.z = __shfl(cz, src);
      bi.w = __shfl(cw, src);
      const bool sA = keepA && (iou_f(bA, bi) > 0.5f);
      const bool sB = keepB && (iou_f(bB, bi) > 0.5f);
      const unsigned long long m = __ballot(sA) | __ballot(sB);
      const bool supp = (m != 0ull);
      if (!hi && lane == i) keepA = validA && !supp;
      if (hi && lane == (i - 64)) keepB = validB && !supp;
    }
    per_scores[(size_t)c * MM + lane] = keepA ? vA : NEGV;
    per_idx[(size_t)c * MM + lane] = iA;
    per_scores[(size_t)c * MM + lane + 64] = keepB ? vB : NEGV;
    per_idx[(size_t)c * MM + lane + 64] = iB;
    if (keepA) atomicAdd(&hist1[fmono(vA) >> 16], 1u);
    if (keepB) atomicAdd(&hist1[fmono(vB) >> 16], 1u);
  }
}

// ---------------- global top-300: two-level radix threshold + compact + small sort ----------
__global__ __launch_bounds__(1024) void k_sel1(const unsigned* __restrict__ hist, int* __restrict__ sel) {
  __shared__ unsigned red[1024];
  const int t = threadIdx.x;
  unsigned s = 0;
#pragma unroll 8
  for (int i = 0; i < 64; i++) s += hist[t * 64 + i];
  red[t] = s;
  __syncthreads();
  for (int off = 1; off < 1024; off <<= 1) {
    unsigned add = (t + off < 1024) ? red[t + off] : 0u;
    __syncthreads();
    red[t] += add;
    __syncthreads();
  }
  unsigned above = (t < 1023) ? red[t + 1] : 0u;
  if (red[t] >= (unsigned)TOPKN && above < (unsigned)TOPKN) {
    unsigned run = above;
    for (int b = 63; b >= 0; --b) {
      unsigned cb = hist[t * 64 + b];
      if (run < (unsigned)TOPKN && run + cb >= (unsigned)TOPKN) {
        sel[0] = t * 64 + b;
        sel[1] = (int)((unsigned)TOPKN - run);
      }
      run += cb;
    }
  }
}

__global__ __launch_bounds__(256) void k_hist2(const float* __restrict__ per_scores,
                                               const int* __restrict__ sel,
                                               unsigned* __restrict__ hist2) {
  const int f = blockIdx.x * 256 + threadIdx.x;
  if (f >= NFLAT) return;
  const unsigned p16 = (unsigned)sel[0];
  unsigned u = fmono(per_scores[f]);
  if ((u >> 16) == p16) atomicAdd(&hist2[u & 0xFFFFu], 1u);
}

__global__ __launch_bounds__(1024) void k_sel2(const unsigned* __restrict__ hist, int* __restrict__ sel) {
  __shared__ unsigned red[1024];
  __shared__ unsigned sneed, sp16;
  const int t = threadIdx.x;
  if (t == 0) { sneed = (unsigned)sel[1]; sp16 = (unsigned)sel[0]; }
  __syncthreads();
  const unsigned NEED = sneed;
  unsigned s = 0;
#pragma unroll 8
  for (int i = 0; i < 64; i++) s += hist[t * 64 + i];
  red[t] = s;
  __syncthreads();
  for (int off = 1; off < 1024; off <<= 1) {
    unsigned add = (t + off < 1024) ? red[t + off] : 0u;
    __syncthreads();
    red[t] += add;
    __syncthreads();
  }
  unsigned above = (t < 1023) ? red[t + 1] : 0u;
  if (red[t] >= NEED && above < NEED) {
    unsigned run = above;
    for (int b = 63; b >= 0; --b) {
      unsigned cb = hist[t * 64 + b];
      if (run < NEED && run + cb >= NEED) {
        sel[2] = (int)((sp16 << 16) | (unsigned)(t * 64 + b));
      }
      run += cb;
    }
  }
}

__global__ __launch_bounds__(256) void k_compact(const float* __restrict__ per_scores,
                                                 int* __restrict__ sel,
                                                 uint64_t* __restrict__ deflist,
                                                 uint64_t* __restrict__ tielist) {
  const int f = blockIdx.x * 256 + threadIdx.x;
  if (f >= NFLAT) return;
  const unsigned v32 = (unsigned)sel[2];
  unsigned u = fmono(per_scores[f]);
  if (u < v32) return;
  uint64_t key = ((uint64_t)u << 18) | (uint64_t)(262143 - f);
  if (u > v32) {
    int p = atomicAdd(&sel[4], 1);
    if (p < 512) deflist[p] = key;
  } else {
    int p = atomicAdd(&sel[5], 1);
    if (p < 512) tielist[p] = key;
  }
}

__global__ __launch_bounds__(1024) void k_final(const uint64_t* __restrict__ deflist,
                                                const uint64_t* __restrict__ tielist,
                                                const int* __restrict__ sel,
                                                const int* __restrict__ per_idx,
                                                const float* __restrict__ boxes,
                                                float* __restrict__ out) {
  __shared__ uint64_t skey[1024];
  const int t = threadIdx.x;
  const int n0 = min(sel[4], 512);
  const int n1 = min(sel[5], 512);
  uint64_t k = 0;
  if (t < n0) k = deflist[t];
  else if (t - n0 < n1) k = tielist[t - n0];
  skey[t] = k;
  __syncthreads();
  for (int kk2 = 2; kk2 <= 1024; kk2 <<= 1)
    for (int j = kk2 >> 1; j > 0; j >>= 1) {
      __syncthreads();
      int ixj = t ^ j;
      if (ixj > t) {
        uint64_t a = skey[t], b = skey[ixj];
        bool desc = ((t & kk2) == 0);
        if (desc ? (a < b) : (a > b)) { skey[t] = b; skey[ixj] = a; }
      }
    }
  __syncthreads();
  if (t < TOPKN) {
    uint64_t key = skey[t];
    int f = 262143 - (int)(key & 0x3FFFFu);
    float val = monof((unsigned)(key >> 18));
    int cls = f >> 7;
    int prop = per_idx[f];
    float4 b = *(const float4*)&boxes[prop * 4];
    float* o = &out[t * 6];
    o[0] = b.x; o[1] = b.y; o[2] = b.z; o[3] = b.w;
    o[4] = val; o[5] = (float)cls;
  }
}

extern "C" void kernel_launch(void* const* d_in, const int* in_sizes, int n_in,
                              void* d_out, int out_size, void* d_ws, size_t ws_size,
                              hipStream_t stream) {
  const float* feat = (const float*)d_in[0];
  const float* props = (const float*)d_in[1];
  const float* wcls = (const float*)d_in[2];
  const float* bcls = (const float*)d_in[3];
  const float* wbox = (const float*)d_in[4];
  const float* bbox = (const float*)d_in[5];
  float* out = (float*)d_out;
  char* ws = (char*)d_ws;

  size_t o = 0;
  auto al = [&](size_t b) { size_t cur = o; o += (b + 255) & ~(size_t)255; return cur; };
  const size_t o_boxes = al((size_t)RR * 4 * 4);
  const size_t o_ps = al((size_t)KCLS * MM * 4);
  const size_t o_pi = al((size_t)KCLS * MM * 4);
  const size_t o_rmax = al((size_t)RR * 8);
  const size_t o_rsum = al((size_t)RR * 8);
  const size_t o_hist1 = al((size_t)65536 * 4);
  const size_t o_hist2 = al((size_t)65536 * 4);
  const size_t o_sel = al((size_t)256);
  const size_t o_def = al((size_t)512 * 8);
  const size_t o_tie = al((size_t)512 * 8);
  const size_t fixed_end = o;

  float* boxes = (float*)(ws + o_boxes);
  float* per_scores = (float*)(ws + o_ps);
  int* per_idx = (int*)(ws + o_pi);
  double* rmax = (double*)(ws + o_rmax);
  double* rsum = (double*)(ws + o_rsum);
  unsigned* hist1 = (unsigned*)(ws + o_hist1);
  unsigned* hist2 = (unsigned*)(ws + o_hist2);
  int* sel = (int*)(ws + o_sel);
  uint64_t* deflist = (uint64_t*)(ws + o_def);
  uint64_t* tielist = (uint64_t*)(ws + o_tie);

  // MFMA-path layout (with aliasing): A-planes (also scoresA), Bt-planes, logits (also scoresT)
  const size_t sz_A3 = ((size_t)3 * RR * DD * 2 + 255) & ~(size_t)255;      // 50.3 MB
  const size_t sz_Bt = ((size_t)3 * NB * DD * 2 + 255) & ~(size_t)255;      // 7.9 MB
  const size_t sz_lg2 = ((size_t)RR * KP2 * 8 + 255) & ~(size_t)255;        // 79.7 MB
  const size_t needM = fixed_end + sz_A3 + sz_Bt + sz_lg2;

  const size_t sz_scT = ((size_t)KCLS * RR * 4 + 255) & ~(size_t)255;
  const size_t sz_lgD = ((size_t)RR * KP * 8 + 255) & ~(size_t)255;
  const size_t sz_lgF = ((size_t)RR * KP * 4 + 255) & ~(size_t)255;

  const bool pathM = ws_size >= needM;
  const bool pathA = !pathM && ws_size >= fixed_end + sz_scT + sz_lgD;
  const bool pathB = !pathM && !pathA && ws_size >= fixed_end + sz_scT + sz_lgF;

  const int gFlat = (NFLAT + 255) / 256;

  hipMemsetAsync(ws + o_hist1, 0, (o_sel - o_hist1) + 256, stream);

  k_boxes<<<RR / 4, 256, 0, stream>>>(feat, wbox, bbox, props, boxes);

  if (pathM) {
    unsigned short* Ap = (unsigned short*)(ws + fixed_end);
    unsigned short* Btp = (unsigned short*)(ws + fixed_end + sz_A3);
    double* lg = (double*)(ws + fixed_end + sz_A3 + sz_Bt);
    float* scoresA = (float*)(ws + fixed_end);                 // aliases Ap (dead after GEMM)
    float* scoresT = (float*)(ws + fixed_end + sz_A3 + sz_Bt); // aliases lg (dead after softmax)

    k_split_feat<<<(RR * DD / 4) / 256, 256, 0, stream>>>(feat, Ap);
    k_split_w<<<dim3(NB / 64, DD / 64), 256, 0, stream>>>(wcls, Btp);
    k_gemm_mfma<<<dim3(NB / 128, RR / 128), 512, 0, stream>>>(Ap, Btp, bcls, lg);
    k_softmax<<<RR, 256, 0, stream>>>(lg, scoresA);
    k_transposeS<<<dim3(KP2 / 64, RR / 64), 256, 0, stream>>>(scoresA, scoresT);
    k_class<false><<<KCLS, 256, 0, stream>>>(scoresT, nullptr, rmax, rsum, boxes, per_scores, per_idx, hist1);
  } else if (pathA) {
    float* scoresT = (float*)(ws + fixed_end);
    double* lg = (double*)(ws + fixed_end + sz_scT);
    k_gemm<double><<<dim3(19, 128), 256, 0, stream>>>(feat, wcls, bcls, lg);
    k_rowstats<double><<<RR, 256, 0, stream>>>(lg, rmax, rsum);
    k_scores<double><<<dim3(19, 128), 256, 0, stream>>>(lg, rmax, rsum, scoresT);
    k_class<false><<<KCLS, 256, 0, stream>>>(scoresT, nullptr, rmax, rsum, boxes, per_scores, per_idx, hist1);
  } else if (pathB) {
    float* scoresT = (float*)(ws + fixed_end);
    float* lg = (float*)(ws + fixed_end + sz_scT);
    k_gemm<float><<<dim3(19, 128), 256, 0, stream>>>(feat, wcls, bcls, lg);
    k_rowstats<float><<<RR, 256, 0, stream>>>(lg, rmax, rsum);
    k_scores<float><<<dim3(19, 128), 256, 0, stream>>>(lg, rmax, rsum, scoresT);
    k_class<false><<<KCLS, 256, 0, stream>>>(scoresT, nullptr, rmax, rsum, boxes, per_scores, per_idx, hist1);
  } else {
    float* lg = (float*)(ws + fixed_end);
    k_gemm<float><<<dim3(19, 128), 256, 0, stream>>>(feat, wcls, bcls, lg);
    k_rowstats<float><<<RR, 256, 0, stream>>>(lg, rmax, rsum);
    k_class<true><<<KCLS, 256, 0, stream>>>(nullptr, lg, rmax, rsum, boxes, per_scores, per_idx, hist1);
  }

  k_sel1<<<1, 1024, 0, stream>>>(hist1, sel);
  k_hist2<<<gFlat, 256, 0, stream>>>(per_scores, sel, hist2);
  k_sel2<<<1, 1024, 0, stream>>>(hist2, sel);
  k_compact<<<gFlat, 256, 0, stream>>>(per_scores, sel, deflist, tielist);
  k_final<<<1, 1024, 0, stream>>>(deflist, tielist, sel, per_idx, boxes, out);
}